// Round 1
// baseline (9170.256 us; speedup 1.0000x reference)
//
#include <hip/hip_runtime.h>
#include <cmath>

#define B_  2
#define T_  1024
#define D_  1024
#define H_  16
#define HD_ 64
#define FF_ 4096
#define L_  4
#define M_  128

typedef __bf16 bf16x8 __attribute__((ext_vector_type(8)));
typedef float f32x4 __attribute__((ext_vector_type(4)));

// ---------------------------------------------------------------------------
// Generic GEMM: C[M,N] = A[M,K] @ W[K,N] + bias[N] (+ res[M,N] if res != null)
// bf16 MFMA 16x16x32, 64x64 tile, 4 waves (2x2), each wave 32x32 (2x2 subtiles)
// ---------------------------------------------------------------------------
__global__ __launch_bounds__(256) void gemm_kernel(
    const float* __restrict__ A, const float* __restrict__ W,
    const float* __restrict__ bias, const float* __restrict__ res,
    float* __restrict__ C, int M, int N, int K)
{
    __shared__ __bf16 As[64][40];   // row-major, padded stride 40
    __shared__ __bf16 Bs[64][40];   // n-major (transposed), padded stride 40

    const int tid  = threadIdx.x;
    const int lane = tid & 63;
    const int wave = tid >> 6;
    const int wm   = wave & 1;
    const int wn   = wave >> 1;
    const int quad = lane >> 4;
    const int l16  = lane & 15;
    const int m0   = blockIdx.y * 64;
    const int n0   = blockIdx.x * 64;

    // staging indices
    const int ar = tid >> 2;          // 0..63 (A row)
    const int ac = (tid & 3) * 8;     // 0,8,16,24 (A col base)
    const int bk = tid >> 3;          // 0..31 (W row = k)
    const int bn = (tid & 7) * 8;     // 0..56 (W col base)

    f32x4 acc[2][2] = {};

    for (int k0 = 0; k0 < K; k0 += 32) {
        // stage A tile (64 x 32), f32 -> bf16
        const float* ap = A + (size_t)(m0 + ar) * K + k0 + ac;
        f32x4 a0 = *(const f32x4*)ap;
        f32x4 a1 = *(const f32x4*)(ap + 4);
        #pragma unroll
        for (int j = 0; j < 4; j++) As[ar][ac + j]     = (__bf16)a0[j];
        #pragma unroll
        for (int j = 0; j < 4; j++) As[ar][ac + 4 + j] = (__bf16)a1[j];
        // stage B tile (32 x 64) transposed into Bs[n][k]
        const float* wp = W + (size_t)(k0 + bk) * N + n0 + bn;
        f32x4 b0 = *(const f32x4*)wp;
        f32x4 b1 = *(const f32x4*)(wp + 4);
        #pragma unroll
        for (int j = 0; j < 4; j++) Bs[bn + j][bk]     = (__bf16)b0[j];
        #pragma unroll
        for (int j = 0; j < 4; j++) Bs[bn + 4 + j][bk] = (__bf16)b1[j];
        __syncthreads();

        bf16x8 afrag[2], bfrag[2];
        #pragma unroll
        for (int mi = 0; mi < 2; mi++)
            afrag[mi] = *(const bf16x8*)&As[wm * 32 + mi * 16 + l16][quad * 8];
        #pragma unroll
        for (int ni = 0; ni < 2; ni++)
            bfrag[ni] = *(const bf16x8*)&Bs[wn * 32 + ni * 16 + l16][quad * 8];

        #pragma unroll
        for (int mi = 0; mi < 2; mi++)
            #pragma unroll
            for (int ni = 0; ni < 2; ni++)
                acc[mi][ni] = __builtin_amdgcn_mfma_f32_16x16x32_bf16(
                    afrag[mi], bfrag[ni], acc[mi][ni], 0, 0, 0);
        __syncthreads();
    }

    // epilogue: C/D layout col = lane&15, row = quad*4 + r  (m89/m91 verified)
    #pragma unroll
    for (int mi = 0; mi < 2; mi++) {
        #pragma unroll
        for (int ni = 0; ni < 2; ni++) {
            int col = n0 + wn * 32 + ni * 16 + l16;
            #pragma unroll
            for (int r = 0; r < 4; r++) {
                int row = m0 + wm * 32 + mi * 16 + quad * 4 + r;
                float v = acc[mi][ni][r] + bias[col];
                if (res) v += res[(size_t)row * N + col];
                C[(size_t)row * N + col] = v;
            }
        }
    }
}

// ---------------------------------------------------------------------------
// LayerNorm over D=1024, one block per row; optional per-col bias add and
// full-tensor add folded into the input (for the input projection fusion).
// ---------------------------------------------------------------------------
__global__ __launch_bounds__(256) void ln_kernel(
    const float* __restrict__ in, const float* __restrict__ addb,
    const float* __restrict__ addf,
    const float* __restrict__ g, const float* __restrict__ b,
    float* __restrict__ out)
{
    int row = blockIdx.x;
    int t = threadIdx.x;
    __shared__ float red[256];
    __shared__ float red2[256];
    const float* ip = in + (size_t)row * D_;
    float v[4];
    float sum = 0.f, sumsq = 0.f;
    #pragma unroll
    for (int j = 0; j < 4; j++) {
        int c = t + j * 256;
        float x = ip[c];
        if (addb) x += addb[c];
        if (addf) x += addf[(size_t)row * D_ + c];
        v[j] = x;
        sum += x; sumsq += x * x;
    }
    red[t] = sum; red2[t] = sumsq;
    __syncthreads();
    for (int s = 128; s > 0; s >>= 1) {
        if (t < s) { red[t] += red[t + s]; red2[t] += red2[t + s]; }
        __syncthreads();
    }
    float mean = red[0] * (1.0f / D_);
    float var  = red2[0] * (1.0f / D_) - mean * mean;
    float rstd = rsqrtf(var + 1e-5f);
    #pragma unroll
    for (int j = 0; j < 4; j++) {
        int c = t + j * 256;
        out[(size_t)row * D_ + c] = (v[j] - mean) * rstd * g[c] + b[c];
    }
}

// ---------------------------------------------------------------------------
// RoPE applied in-place to q and k slices of the qkv buffer (B,T,3,H,HD)
// pair i uses freq 10000^(-((2i) mod 32)/32); even/odd interleaved.
// ---------------------------------------------------------------------------
__global__ __launch_bounds__(256) void rope_kernel(float* __restrict__ qkv)
{
    int idx = blockIdx.x * 256 + threadIdx.x;    // B*T*H*32 = 1,048,576
    int i = idx & 31;
    int h = (idx >> 5) & (H_ - 1);
    int t = (idx >> 9) & (T_ - 1);
    int b = idx >> 19;
    int j = (2 * i) & 31;
    float f = powf(10000.0f, -(float)j / 32.0f);
    float ang = (float)t * f;
    float c = cosf(ang);
    float s = sinf(ang);
    size_t base = ((size_t)(b * T_ + t) * 3) * D_ + h * HD_ + 2 * i;
    #pragma unroll
    for (int s01 = 0; s01 < 2; s01++) {
        float2* p = (float2*)(qkv + base + (size_t)s01 * D_);
        float2 x = *p;
        float2 y;
        y.x = x.x * c - x.y * s;
        y.y = x.x * s + x.y * c;
        *p = y;
    }
}

// ---------------------------------------------------------------------------
// Fused attention: one block per (b,h,q). Scores in LDS, softmax, PV.
// rb points at this layer's rel_bias (2M+1, H).
// ---------------------------------------------------------------------------
__global__ __launch_bounds__(256) void attn_kernel(
    const float* __restrict__ qkv, const float* __restrict__ rb,
    float* __restrict__ out)
{
    int q = blockIdx.x & (T_ - 1);
    int h = (blockIdx.x >> 10) & (H_ - 1);
    int b = blockIdx.x >> 14;
    int t = threadIdx.x;
    __shared__ float qs[HD_];
    __shared__ float ss[T_];
    __shared__ float red[256];
    __shared__ float pv[4][HD_];

    const float* qp = qkv + ((size_t)(b * T_ + q) * 3) * D_ + h * HD_;
    if (t < HD_) qs[t] = qp[t];
    __syncthreads();

    float lmax = -1e30f;
    float sv[4];
    #pragma unroll
    for (int kk = 0; kk < 4; kk++) {
        int k = t + kk * 256;
        const float* kp = qkv + ((size_t)(b * T_ + k) * 3 + 1) * D_ + h * HD_;
        float dot = 0.f;
        #pragma unroll
        for (int d = 0; d < HD_; d += 4) {
            f32x4 kv = *(const f32x4*)(kp + d);
            dot += kv[0] * qs[d] + kv[1] * qs[d + 1] + kv[2] * qs[d + 2] + kv[3] * qs[d + 3];
        }
        int r = k - q;
        r = (r < -M_) ? -M_ : (r > M_ ? M_ : r);
        r += M_;
        float sc = dot * 0.125f + rb[r * H_ + h];
        sv[kk] = sc;
        lmax = fmaxf(lmax, sc);
    }
    red[t] = lmax; __syncthreads();
    for (int s2 = 128; s2 > 0; s2 >>= 1) {
        if (t < s2) red[t] = fmaxf(red[t], red[t + s2]);
        __syncthreads();
    }
    float smax = red[0];
    __syncthreads();

    float lsum = 0.f;
    #pragma unroll
    for (int kk = 0; kk < 4; kk++) {
        float e = expf(sv[kk] - smax);
        ss[t + kk * 256] = e;
        lsum += e;
    }
    red[t] = lsum; __syncthreads();
    for (int s2 = 128; s2 > 0; s2 >>= 1) {
        if (t < s2) red[t] += red[t + s2];
        __syncthreads();
    }
    float inv = 1.0f / red[0];

    int w = t >> 6, d = t & 63;
    const float* vbase = qkv + ((size_t)(b * T_) * 3 + 2) * D_ + h * HD_ + d;
    float a0 = 0, a1 = 0, a2 = 0, a3 = 0;
    int kbase = w * 256;
    for (int k = 0; k < 256; k += 4) {
        int kk = kbase + k;
        a0 += ss[kk]     * vbase[(size_t)(kk)     * 3 * D_];
        a1 += ss[kk + 1] * vbase[(size_t)(kk + 1) * 3 * D_];
        a2 += ss[kk + 2] * vbase[(size_t)(kk + 2) * 3 * D_];
        a3 += ss[kk + 3] * vbase[(size_t)(kk + 3) * 3 * D_];
    }
    pv[w][d] = a0 + a1 + a2 + a3;
    __syncthreads();
    if (t < HD_) {
        float o = (pv[0][t] + pv[1][t] + pv[2][t] + pv[3][t]) * inv;
        out[(size_t)(b * T_ + q) * D_ + h * HD_ + t] = o;
    }
}

// ---------------------------------------------------------------------------
// GLU: cc[m][f] = ab[m][f] * gelu_exact(ab[m][FF+f])
// ---------------------------------------------------------------------------
__global__ __launch_bounds__(256) void glu_kernel(
    const float* __restrict__ ab, float* __restrict__ cc)
{
    size_t idx = (size_t)blockIdx.x * 256 + threadIdx.x;  // 2048*4096
    size_t m = idx >> 12;
    size_t f = idx & 4095;
    float a = ab[m * (2 * FF_) + f];
    float g = ab[m * (2 * FF_) + FF_ + f];
    float ge = 0.5f * g * (1.0f + erff(g * 0.7071067811865475f));
    cc[idx] = a * ge;
}

// ---------------------------------------------------------------------------
// Final: per-row norm, scale, clip, add.
// ---------------------------------------------------------------------------
__global__ __launch_bounds__(256) void final_kernel(
    const float* __restrict__ o, const float* __restrict__ alpha,
    const float* __restrict__ beta, const float* __restrict__ alpha_scale,
    const float* __restrict__ beta_scale, float* __restrict__ outp)
{
    int row = blockIdx.x;
    int t = threadIdx.x;
    __shared__ float red[256];
    const float* op = o + (size_t)row * D_;
    float v[4];
    float sumsq = 0.f;
    #pragma unroll
    for (int j = 0; j < 4; j++) {
        float x = op[t + j * 256];
        v[j] = x;
        sumsq += x * x;
    }
    red[t] = sumsq; __syncthreads();
    for (int s = 128; s > 0; s >>= 1) {
        if (t < s) red[t] += red[t + s];
        __syncthreads();
    }
    float ms = sqrtf(red[0]);
    float as = fminf(fmaxf(alpha_scale[0], 0.f), 1.f);
    float sc = 1.0f + alpha[0] * as * fminf(ms, 5.0f);
    float bb = beta[0] * beta_scale[0];
    #pragma unroll
    for (int j = 0; j < 4; j++) {
        float x = v[j] * sc + bb;
        x = fminf(fmaxf(x, -10.f), 10.f);
        outp[(size_t)row * D_ + t + j * 256] = x + v[j];
    }
}

// ---------------------------------------------------------------------------
extern "C" void kernel_launch(void* const* d_in, const int* in_sizes, int n_in,
                              void* d_out, int out_size, void* d_ws, size_t ws_size,
                              hipStream_t stream)
{
    const float* x        = (const float*)d_in[0];
    const float* context  = (const float*)d_in[1];
    const float* W_in     = (const float*)d_in[2];
    const float* b_in     = (const float*)d_in[3];
    const float* ln_in_g  = (const float*)d_in[4];
    const float* ln_in_b  = (const float*)d_in[5];
    const float* ln1_g    = (const float*)d_in[6];
    const float* ln1_b    = (const float*)d_in[7];
    const float* Wqkv     = (const float*)d_in[8];
    const float* bqkv     = (const float*)d_in[9];
    const float* Wproj    = (const float*)d_in[10];
    const float* bproj    = (const float*)d_in[11];
    const float* rel_bias = (const float*)d_in[12];
    const float* ln2_g    = (const float*)d_in[13];
    const float* ln2_b    = (const float*)d_in[14];
    const float* Wfc1     = (const float*)d_in[15];
    const float* bfc1     = (const float*)d_in[16];
    const float* Wfc2     = (const float*)d_in[17];
    const float* bfc2     = (const float*)d_in[18];
    const float* ln_f_g   = (const float*)d_in[19];
    const float* ln_f_b   = (const float*)d_in[20];
    const float* W_out    = (const float*)d_in[21];
    const float* b_out    = (const float*)d_in[22];
    const float* alpha    = (const float*)d_in[23];
    const float* beta     = (const float*)d_in[24];
    const float* alpha_s  = (const float*)d_in[25];
    const float* beta_s   = (const float*)d_in[26];

    float* ws = (float*)d_ws;
    const size_t MROWS = (size_t)B_ * T_;          // 2048
    float* h       = ws;                            // 2M floats
    float* hn      = ws + 2 * 1024 * 1024;          // 2M floats
    float* big     = ws + 4 * 1024 * 1024;          // qkv (6M) / ab (16M) / o (2M)
    float* attnout = ws + 10 * 1024 * 1024;         // 2M floats
    float* cc      = ws + 20 * 1024 * 1024;         // 8M floats (ends at 28M = 112MB)

    dim3 blk(256);
    const int MB = (int)MROWS / 64;                 // 32

    // h = LN(x @ W_in + b_in + context)
    gemm_kernel<<<dim3(D_ / 64, MB), blk, 0, stream>>>(x, W_in, b_in, context, big,
                                                       (int)MROWS, D_, D_);
    ln_kernel<<<dim3((int)MROWS), blk, 0, stream>>>(big, nullptr, nullptr,
                                                    ln_in_g, ln_in_b, h);

    for (int l = 0; l < L_; l++) {
        const float* wqkv = Wqkv + (size_t)l * D_ * 3 * D_;
        const float* bq   = bqkv + (size_t)l * 3 * D_;
        const float* wp   = Wproj + (size_t)l * D_ * D_;
        const float* bp   = bproj + (size_t)l * D_;
        const float* rb   = rel_bias + (size_t)l * (2 * M_ + 1) * H_;
        const float* w1   = Wfc1 + (size_t)l * D_ * 2 * FF_;
        const float* bf1  = bfc1 + (size_t)l * 2 * FF_;
        const float* w2   = Wfc2 + (size_t)l * FF_ * D_;
        const float* bf2  = bfc2 + (size_t)l * D_;

        // hn = LN(h)
        ln_kernel<<<dim3((int)MROWS), blk, 0, stream>>>(h, nullptr, nullptr,
                                                        ln1_g + l * D_, ln1_b + l * D_, hn);
        // qkv = hn @ Wqkv + bqkv
        gemm_kernel<<<dim3(3 * D_ / 64, MB), blk, 0, stream>>>(hn, wqkv, bq, nullptr, big,
                                                               (int)MROWS, 3 * D_, D_);
        // RoPE in-place on q,k
        rope_kernel<<<dim3(B_ * T_ * H_ * 32 / 256), blk, 0, stream>>>(big);
        // attention
        attn_kernel<<<dim3(B_ * H_ * T_), blk, 0, stream>>>(big, rb, attnout);
        // h = h + attnout @ Wproj + bproj
        gemm_kernel<<<dim3(D_ / 64, MB), blk, 0, stream>>>(attnout, wp, bp, h, h,
                                                           (int)MROWS, D_, D_);
        // hn = LN(h)
        ln_kernel<<<dim3((int)MROWS), blk, 0, stream>>>(h, nullptr, nullptr,
                                                        ln2_g + l * D_, ln2_b + l * D_, hn);
        // ab = hn @ Wfc1 + bfc1   (N = 8192)
        gemm_kernel<<<dim3(2 * FF_ / 64, MB), blk, 0, stream>>>(hn, w1, bf1, nullptr, big,
                                                                (int)MROWS, 2 * FF_, D_);
        // cc = a * gelu(gate)
        glu_kernel<<<dim3((int)(MROWS * FF_ / 256)), blk, 0, stream>>>(big, cc);
        // h = h + cc @ Wfc2 + bfc2   (K = 4096)
        gemm_kernel<<<dim3(D_ / 64, MB), blk, 0, stream>>>(cc, w2, bf2, h, h,
                                                           (int)MROWS, D_, FF_);
    }

    // hf = LN(h); o = hf @ W_out + b_out
    ln_kernel<<<dim3((int)MROWS), blk, 0, stream>>>(h, nullptr, nullptr, ln_f_g, ln_f_b, hn);
    gemm_kernel<<<dim3(D_ / 64, MB), blk, 0, stream>>>(hn, W_out, b_out, nullptr, big,
                                                       (int)MROWS, D_, D_);
    // final scale/clip
    final_kernel<<<dim3((int)MROWS), blk, 0, stream>>>(big, alpha, beta, alpha_s, beta_s,
                                                       (float*)d_out);
}

// Round 2
// 2464.688 us; speedup vs baseline: 3.7207x; 3.7207x over previous
//
#include <hip/hip_runtime.h>
#include <cmath>

#define B_  2
#define T_  1024
#define D_  1024
#define H_  16
#define HD_ 64
#define FF_ 4096
#define L_  4
#define M_  128

typedef __bf16 bf16x8 __attribute__((ext_vector_type(8)));
typedef __bf16 bf16x4 __attribute__((ext_vector_type(4)));
typedef float f32x4 __attribute__((ext_vector_type(4)));

// ---------------------------------------------------------------------------
// Generic GEMM: C[M,N] = A[M,K] @ W[K,N] + bias[N] (+ res[M,N] if res != null)
// bf16 MFMA 16x16x32, 64x64 tile, 4 waves (2x2), each wave 32x32 (2x2 subtiles)
// ---------------------------------------------------------------------------
__global__ __launch_bounds__(256) void gemm_kernel(
    const float* __restrict__ A, const float* __restrict__ W,
    const float* __restrict__ bias, const float* __restrict__ res,
    float* __restrict__ C, int M, int N, int K)
{
    __shared__ __bf16 As[64][40];   // row-major, padded stride 40
    __shared__ __bf16 Bs[64][40];   // n-major (transposed), padded stride 40

    const int tid  = threadIdx.x;
    const int lane = tid & 63;
    const int wave = tid >> 6;
    const int wm   = wave & 1;
    const int wn   = wave >> 1;
    const int quad = lane >> 4;
    const int l16  = lane & 15;
    const int m0   = blockIdx.y * 64;
    const int n0   = blockIdx.x * 64;

    const int ar = tid >> 2;          // 0..63 (A row)
    const int ac = (tid & 3) * 8;     // A col base
    const int bk = tid >> 3;          // 0..31 (W row = k)
    const int bn = (tid & 7) * 8;     // W col base

    f32x4 acc[2][2] = {};

    for (int k0 = 0; k0 < K; k0 += 32) {
        const float* ap = A + (size_t)(m0 + ar) * K + k0 + ac;
        f32x4 a0 = *(const f32x4*)ap;
        f32x4 a1 = *(const f32x4*)(ap + 4);
        #pragma unroll
        for (int j = 0; j < 4; j++) As[ar][ac + j]     = (__bf16)a0[j];
        #pragma unroll
        for (int j = 0; j < 4; j++) As[ar][ac + 4 + j] = (__bf16)a1[j];
        const float* wp = W + (size_t)(k0 + bk) * N + n0 + bn;
        f32x4 b0 = *(const f32x4*)wp;
        f32x4 b1 = *(const f32x4*)(wp + 4);
        #pragma unroll
        for (int j = 0; j < 4; j++) Bs[bn + j][bk]     = (__bf16)b0[j];
        #pragma unroll
        for (int j = 0; j < 4; j++) Bs[bn + 4 + j][bk] = (__bf16)b1[j];
        __syncthreads();

        bf16x8 afrag[2], bfrag[2];
        #pragma unroll
        for (int mi = 0; mi < 2; mi++)
            afrag[mi] = *(const bf16x8*)&As[wm * 32 + mi * 16 + l16][quad * 8];
        #pragma unroll
        for (int ni = 0; ni < 2; ni++)
            bfrag[ni] = *(const bf16x8*)&Bs[wn * 32 + ni * 16 + l16][quad * 8];

        #pragma unroll
        for (int mi = 0; mi < 2; mi++)
            #pragma unroll
            for (int ni = 0; ni < 2; ni++)
                acc[mi][ni] = __builtin_amdgcn_mfma_f32_16x16x32_bf16(
                    afrag[mi], bfrag[ni], acc[mi][ni], 0, 0, 0);
        __syncthreads();
    }

    #pragma unroll
    for (int mi = 0; mi < 2; mi++) {
        #pragma unroll
        for (int ni = 0; ni < 2; ni++) {
            int col = n0 + wn * 32 + ni * 16 + l16;
            #pragma unroll
            for (int r = 0; r < 4; r++) {
                int row = m0 + wm * 32 + mi * 16 + quad * 4 + r;
                float v = acc[mi][ni][r] + bias[col];
                if (res) v += res[(size_t)row * N + col];
                C[(size_t)row * N + col] = v;
            }
        }
    }
}

// ---------------------------------------------------------------------------
// LayerNorm over D=1024, one block per row.
// ---------------------------------------------------------------------------
__global__ __launch_bounds__(256) void ln_kernel(
    const float* __restrict__ in,
    const float* __restrict__ g, const float* __restrict__ b,
    float* __restrict__ out)
{
    int row = blockIdx.x;
    int t = threadIdx.x;
    __shared__ float red[256];
    __shared__ float red2[256];
    const float* ip = in + (size_t)row * D_;
    float v[4];
    float sum = 0.f, sumsq = 0.f;
    #pragma unroll
    for (int j = 0; j < 4; j++) {
        int c = t + j * 256;
        float x = ip[c];
        v[j] = x;
        sum += x; sumsq += x * x;
    }
    red[t] = sum; red2[t] = sumsq;
    __syncthreads();
    for (int s = 128; s > 0; s >>= 1) {
        if (t < s) { red[t] += red[t + s]; red2[t] += red2[t + s]; }
        __syncthreads();
    }
    float mean = red[0] * (1.0f / D_);
    float var  = red2[0] * (1.0f / D_) - mean * mean;
    float rstd = rsqrtf(var + 1e-5f);
    #pragma unroll
    for (int j = 0; j < 4; j++) {
        int c = t + j * 256;
        out[(size_t)row * D_ + c] = (v[j] - mean) * rstd * g[c] + b[c];
    }
}

// ---------------------------------------------------------------------------
// Repack: qkv[B,T,3,H,HD] -> qpk packed [BH][T][HD] (roped), vp [BH][HD][T].
// grid (T/64, B*H), 256 threads.
// ---------------------------------------------------------------------------
__global__ __launch_bounds__(256) void repack_kernel(
    const float* __restrict__ qkv, float* __restrict__ qp,
    float* __restrict__ kp, float* __restrict__ vp)
{
    int bh = blockIdx.y; int h = bh & (H_ - 1); int b = bh >> 4;
    int t0 = blockIdx.x * 64;
    int tid = threadIdx.x;
    __shared__ float vt[64][65];

    int r  = tid >> 2;            // 0..63: t row within tile
    int tg = t0 + r;
    int pb = (tid & 3) * 8;       // pair base
    #pragma unroll
    for (int j = 0; j < 8; j++) {
        int p = pb + j;
        int jj = (2 * p) & 31;
        float f = expf(-(float)jj * (9.210340371976184f / 32.0f)); // 10000^(-jj/32)
        float ang = (float)tg * f;
        float c = cosf(ang), s = sinf(ang);
        const float2 xq = *(const float2*)(qkv + ((size_t)(b * T_ + tg) * 3 + 0) * D_ + h * HD_ + 2 * p);
        float2 yq = { xq.x * c - xq.y * s, xq.x * s + xq.y * c };
        *(float2*)(qp + ((size_t)bh * T_ + tg) * HD_ + 2 * p) = yq;
        const float2 xk = *(const float2*)(qkv + ((size_t)(b * T_ + tg) * 3 + 1) * D_ + h * HD_ + 2 * p);
        float2 yk = { xk.x * c - xk.y * s, xk.x * s + xk.y * c };
        *(float2*)(kp + ((size_t)bh * T_ + tg) * HD_ + 2 * p) = yk;
    }
    // v: transpose 64x64 tile through LDS
    {
        int cb = (tid & 3) * 16;
        const float* vsrc = qkv + ((size_t)(b * T_ + tg) * 3 + 2) * D_ + h * HD_ + cb;
        #pragma unroll
        for (int j = 0; j < 16; j += 4) {
            f32x4 v = *(const f32x4*)(vsrc + j);
            #pragma unroll
            for (int u = 0; u < 4; u++) vt[cb + j + u][r] = v[u];
        }
    }
    __syncthreads();
    {
        int d = tid >> 2, cb = (tid & 3) * 16;
        #pragma unroll
        for (int j = 0; j < 16; j += 4) {
            f32x4 v;
            #pragma unroll
            for (int u = 0; u < 4; u++) v[u] = vt[d][cb + j + u];
            *(f32x4*)(vp + ((size_t)bh * HD_ + d) * T_ + t0 + cb + j) = v;
        }
    }
}

// ---------------------------------------------------------------------------
// Flash-style MFMA attention. grid (T/64, B*H), 256 threads (4 waves).
// Wave w owns q-rows [w*16, w*16+16) of the 64-row q-tile, all 64 cols.
// qp,kp: [BH][T][64] (roped); vp: [BH][64][T]; out: [B,T,D].
// ---------------------------------------------------------------------------
__global__ __launch_bounds__(256) void attn_mfma_kernel(
    const float* __restrict__ qp, const float* __restrict__ kp,
    const float* __restrict__ vp, const float* __restrict__ rb,
    float* __restrict__ out)
{
    int bh = blockIdx.y; int h = bh & (H_ - 1); int b = bh >> 4;
    int q0 = blockIdx.x * 64;
    int tid = threadIdx.x;
    int lane = tid & 63, wave = tid >> 6;
    int quad = lane >> 4, l16 = lane & 15;

    __shared__ __bf16 Qs[64][72];
    __shared__ __bf16 Ks[64][72];
    __shared__ __bf16 Vs[64][72];      // [d][krow]
    __shared__ __bf16 Ps[4][16][72];   // [wave][qrow][kcol]
    __shared__ float rbs[2 * M_ + 1];

    for (int i = tid; i < 2 * M_ + 1; i += 256) rbs[i] = rb[i * H_ + h];

    // stage Q tile (16KB contiguous)
    {
        const float* src = qp + ((size_t)bh * T_ + q0) * HD_;
        #pragma unroll
        for (int i = 0; i < 4; i++) {
            int off = (tid + i * 256) * 4;
            f32x4 v = *(const f32x4*)(src + off);
            int rr = off >> 6, cc = off & 63;
            bf16x4 w;
            #pragma unroll
            for (int u = 0; u < 4; u++) w[u] = (__bf16)v[u];
            *(bf16x4*)&Qs[rr][cc] = w;
        }
    }
    __syncthreads();

    bf16x8 qfrag[2];
    qfrag[0] = *(const bf16x8*)&Qs[wave * 16 + l16][quad * 8];
    qfrag[1] = *(const bf16x8*)&Qs[wave * 16 + l16][32 + quad * 8];

    float m_run[4], l_run[4];
    f32x4 o_acc[4];
    #pragma unroll
    for (int r2 = 0; r2 < 4; r2++) { m_run[r2] = -1e30f; l_run[r2] = 0.f; }
    #pragma unroll
    for (int ni = 0; ni < 4; ni++) o_acc[ni] = (f32x4){0.f, 0.f, 0.f, 0.f};

    const int row_l  = quad * 4;
    const int qrow_g = q0 + wave * 16 + row_l;

    for (int k0 = 0; k0 < T_; k0 += 64) {
        __syncthreads();  // protect Ks/Vs reuse across iterations
        {
            const float* ksrc = kp + ((size_t)bh * T_ + k0) * HD_;
            #pragma unroll
            for (int i = 0; i < 4; i++) {
                int off = (tid + i * 256) * 4;
                f32x4 v = *(const f32x4*)(ksrc + off);
                int rr = off >> 6, cc = off & 63;
                bf16x4 w;
                #pragma unroll
                for (int u = 0; u < 4; u++) w[u] = (__bf16)v[u];
                *(bf16x4*)&Ks[rr][cc] = w;
            }
            #pragma unroll
            for (int i = 0; i < 4; i++) {
                int off = (tid + i * 256) * 4;
                int dd = off >> 6, cc = off & 63;
                f32x4 v = *(const f32x4*)(vp + ((size_t)bh * HD_ + dd) * T_ + k0 + cc);
                bf16x4 w;
                #pragma unroll
                for (int u = 0; u < 4; u++) w[u] = (__bf16)v[u];
                *(bf16x4*)&Vs[dd][cc] = w;
            }
        }
        __syncthreads();

        // S = Q @ Ktile^T  (wave: 16 rows x 64 cols)
        f32x4 s_acc[4];
        #pragma unroll
        for (int ni = 0; ni < 4; ni++) s_acc[ni] = (f32x4){0.f, 0.f, 0.f, 0.f};
        #pragma unroll
        for (int ni = 0; ni < 4; ni++) {
            bf16x8 kf0 = *(const bf16x8*)&Ks[ni * 16 + l16][quad * 8];
            bf16x8 kf1 = *(const bf16x8*)&Ks[ni * 16 + l16][32 + quad * 8];
            s_acc[ni] = __builtin_amdgcn_mfma_f32_16x16x32_bf16(qfrag[0], kf0, s_acc[ni], 0, 0, 0);
            s_acc[ni] = __builtin_amdgcn_mfma_f32_16x16x32_bf16(qfrag[1], kf1, s_acc[ni], 0, 0, 0);
        }

        // scale + rel-bias + online softmax (stats across l16 group only)
        float sv[4][4];
        float rmax[4] = {-1e30f, -1e30f, -1e30f, -1e30f};
        #pragma unroll
        for (int ni = 0; ni < 4; ni++) {
            int colg = k0 + ni * 16 + l16;
            #pragma unroll
            for (int r2 = 0; r2 < 4; r2++) {
                int rel = colg - (qrow_g + r2);
                rel = (rel < -M_) ? -M_ : (rel > M_ ? M_ : rel);
                float s = s_acc[ni][r2] * 0.125f + rbs[rel + M_];
                sv[ni][r2] = s;
                rmax[r2] = fmaxf(rmax[r2], s);
            }
        }
        #pragma unroll
        for (int r2 = 0; r2 < 4; r2++)
            #pragma unroll
            for (int off = 1; off < 16; off <<= 1)
                rmax[r2] = fmaxf(rmax[r2], __shfl_xor(rmax[r2], off, 64));

        float alpha[4], rsum[4];
        #pragma unroll
        for (int r2 = 0; r2 < 4; r2++) {
            float mn = fmaxf(m_run[r2], rmax[r2]);
            alpha[r2] = __expf(m_run[r2] - mn);
            m_run[r2] = mn;
            rsum[r2] = 0.f;
        }
        #pragma unroll
        for (int ni = 0; ni < 4; ni++)
            #pragma unroll
            for (int r2 = 0; r2 < 4; r2++) {
                float p = __expf(sv[ni][r2] - m_run[r2]);
                rsum[r2] += p;
                Ps[wave][row_l + r2][ni * 16 + l16] = (__bf16)p;
            }
        #pragma unroll
        for (int r2 = 0; r2 < 4; r2++) {
            #pragma unroll
            for (int off = 1; off < 16; off <<= 1)
                rsum[r2] += __shfl_xor(rsum[r2], off, 64);
            l_run[r2] = l_run[r2] * alpha[r2] + rsum[r2];
        }
        #pragma unroll
        for (int ni = 0; ni < 4; ni++)
            #pragma unroll
            for (int r2 = 0; r2 < 4; r2++) o_acc[ni][r2] *= alpha[r2];

        // O += P @ Vtile   (A = P[qrow][krow] from LDS, B = Vs[d][krow])
        #pragma unroll
        for (int kk = 0; kk < 2; kk++) {
            bf16x8 pfrag = *(const bf16x8*)&Ps[wave][l16][kk * 32 + quad * 8];
            #pragma unroll
            for (int ni = 0; ni < 4; ni++) {
                bf16x8 vfrag = *(const bf16x8*)&Vs[ni * 16 + l16][kk * 32 + quad * 8];
                o_acc[ni] = __builtin_amdgcn_mfma_f32_16x16x32_bf16(pfrag, vfrag, o_acc[ni], 0, 0, 0);
            }
        }
    }

    // epilogue: out[b, qrow, h*64 + d] = O / l
    #pragma unroll
    for (int ni = 0; ni < 4; ni++) {
        int colg = h * HD_ + ni * 16 + l16;
        #pragma unroll
        for (int r2 = 0; r2 < 4; r2++) {
            int rowg = qrow_g + r2;
            out[(size_t)(b * T_ + rowg) * D_ + colg] = o_acc[ni][r2] / l_run[r2];
        }
    }
}

// ---------------------------------------------------------------------------
// GLU: cc[m][f] = ab[m][f] * gelu_exact(ab[m][FF+f])
// ---------------------------------------------------------------------------
__global__ __launch_bounds__(256) void glu_kernel(
    const float* __restrict__ ab, float* __restrict__ cc)
{
    size_t idx = (size_t)blockIdx.x * 256 + threadIdx.x;
    size_t m = idx >> 12;
    size_t f = idx & 4095;
    float a = ab[m * (2 * FF_) + f];
    float g = ab[m * (2 * FF_) + FF_ + f];
    float ge = 0.5f * g * (1.0f + erff(g * 0.7071067811865475f));
    cc[idx] = a * ge;
}

// ---------------------------------------------------------------------------
// Final: per-row norm, scale, clip, add.
// ---------------------------------------------------------------------------
__global__ __launch_bounds__(256) void final_kernel(
    const float* __restrict__ o, const float* __restrict__ alpha,
    const float* __restrict__ beta, const float* __restrict__ alpha_scale,
    const float* __restrict__ beta_scale, float* __restrict__ outp)
{
    int row = blockIdx.x;
    int t = threadIdx.x;
    __shared__ float red[256];
    const float* op = o + (size_t)row * D_;
    float v[4];
    float sumsq = 0.f;
    #pragma unroll
    for (int j = 0; j < 4; j++) {
        float x = op[t + j * 256];
        v[j] = x;
        sumsq += x * x;
    }
    red[t] = sumsq; __syncthreads();
    for (int s = 128; s > 0; s >>= 1) {
        if (t < s) red[t] += red[t + s];
        __syncthreads();
    }
    float ms = sqrtf(red[0]);
    float as = fminf(fmaxf(alpha_scale[0], 0.f), 1.f);
    float sc = 1.0f + alpha[0] * as * fminf(ms, 5.0f);
    float bb = beta[0] * beta_scale[0];
    #pragma unroll
    for (int j = 0; j < 4; j++) {
        float x = v[j] * sc + bb;
        x = fminf(fmaxf(x, -10.f), 10.f);
        outp[(size_t)row * D_ + t + j * 256] = x + v[j];
    }
}

// ---------------------------------------------------------------------------
// gemm with fused add of context then LN is handled by gemm(res=context) + ln.
// ---------------------------------------------------------------------------
extern "C" void kernel_launch(void* const* d_in, const int* in_sizes, int n_in,
                              void* d_out, int out_size, void* d_ws, size_t ws_size,
                              hipStream_t stream)
{
    const float* x        = (const float*)d_in[0];
    const float* context  = (const float*)d_in[1];
    const float* W_in     = (const float*)d_in[2];
    const float* b_in     = (const float*)d_in[3];
    const float* ln_in_g  = (const float*)d_in[4];
    const float* ln_in_b  = (const float*)d_in[5];
    const float* ln1_g    = (const float*)d_in[6];
    const float* ln1_b    = (const float*)d_in[7];
    const float* Wqkv     = (const float*)d_in[8];
    const float* bqkv     = (const float*)d_in[9];
    const float* Wproj    = (const float*)d_in[10];
    const float* bproj    = (const float*)d_in[11];
    const float* rel_bias = (const float*)d_in[12];
    const float* ln2_g    = (const float*)d_in[13];
    const float* ln2_b    = (const float*)d_in[14];
    const float* Wfc1     = (const float*)d_in[15];
    const float* bfc1     = (const float*)d_in[16];
    const float* Wfc2     = (const float*)d_in[17];
    const float* bfc2     = (const float*)d_in[18];
    const float* ln_f_g   = (const float*)d_in[19];
    const float* ln_f_b   = (const float*)d_in[20];
    const float* W_out    = (const float*)d_in[21];
    const float* b_out    = (const float*)d_in[22];
    const float* alpha    = (const float*)d_in[23];
    const float* beta     = (const float*)d_in[24];
    const float* alpha_s  = (const float*)d_in[25];
    const float* beta_s   = (const float*)d_in[26];

    float* ws = (float*)d_ws;
    const size_t MROWS = (size_t)B_ * T_;          // 2048
    float* h       = ws;                            // 2M floats
    float* hn      = ws + 2 * 1024 * 1024;          // 2M floats
    float* big     = ws + 4 * 1024 * 1024;          // qkv (6M) / ab (16M) / o (2M)
    float* attnout = ws + 10 * 1024 * 1024;         // 2M floats
    float* qpk     = ws + 12 * 1024 * 1024;         // 2M floats
    float* kpk     = ws + 14 * 1024 * 1024;         // 2M floats
    float* vpk     = ws + 16 * 1024 * 1024;         // 2M floats
    float* cc      = ws + 20 * 1024 * 1024;         // 8M floats (ends at 28M)

    dim3 blk(256);
    const int MB = (int)MROWS / 64;                 // 32

    gemm_kernel<<<dim3(D_ / 64, MB), blk, 0, stream>>>(x, W_in, b_in, context, big,
                                                       (int)MROWS, D_, D_);
    ln_kernel<<<dim3((int)MROWS), blk, 0, stream>>>(big, ln_in_g, ln_in_b, h);

    for (int l = 0; l < L_; l++) {
        const float* wqkv = Wqkv + (size_t)l * D_ * 3 * D_;
        const float* bq   = bqkv + (size_t)l * 3 * D_;
        const float* wp   = Wproj + (size_t)l * D_ * D_;
        const float* bp   = bproj + (size_t)l * D_;
        const float* rb   = rel_bias + (size_t)l * (2 * M_ + 1) * H_;
        const float* w1   = Wfc1 + (size_t)l * D_ * 2 * FF_;
        const float* bf1  = bfc1 + (size_t)l * 2 * FF_;
        const float* w2   = Wfc2 + (size_t)l * FF_ * D_;
        const float* bf2  = bfc2 + (size_t)l * D_;

        ln_kernel<<<dim3((int)MROWS), blk, 0, stream>>>(h, ln1_g + l * D_, ln1_b + l * D_, hn);
        gemm_kernel<<<dim3(3 * D_ / 64, MB), blk, 0, stream>>>(hn, wqkv, bq, nullptr, big,
                                                               (int)MROWS, 3 * D_, D_);
        repack_kernel<<<dim3(T_ / 64, B_ * H_), blk, 0, stream>>>(big, qpk, kpk, vpk);
        attn_mfma_kernel<<<dim3(T_ / 64, B_ * H_), blk, 0, stream>>>(qpk, kpk, vpk, rb, attnout);
        gemm_kernel<<<dim3(D_ / 64, MB), blk, 0, stream>>>(attnout, wp, bp, h, h,
                                                           (int)MROWS, D_, D_);
        ln_kernel<<<dim3((int)MROWS), blk, 0, stream>>>(h, ln2_g + l * D_, ln2_b + l * D_, hn);
        gemm_kernel<<<dim3(2 * FF_ / 64, MB), blk, 0, stream>>>(hn, w1, bf1, nullptr, big,
                                                                (int)MROWS, 2 * FF_, D_);
        glu_kernel<<<dim3((int)(MROWS * FF_ / 256)), blk, 0, stream>>>(big, cc);
        gemm_kernel<<<dim3(D_ / 64, MB), blk, 0, stream>>>(cc, w2, bf2, h, h,
                                                           (int)MROWS, D_, FF_);
    }

    ln_kernel<<<dim3((int)MROWS), blk, 0, stream>>>(h, ln_f_g, ln_f_b, hn);
    gemm_kernel<<<dim3(D_ / 64, MB), blk, 0, stream>>>(hn, W_out, b_out, nullptr, big,
                                                       (int)MROWS, D_, D_);
    final_kernel<<<dim3((int)MROWS), blk, 0, stream>>>(big, alpha, beta, alpha_s, beta_s,
                                                       (float*)d_out);
}

// Round 3
// 1449.940 us; speedup vs baseline: 6.3246x; 1.6999x over previous
//
#include <hip/hip_runtime.h>
#include <cmath>

#define B_  2
#define T_  1024
#define D_  1024
#define H_  16
#define HD_ 64
#define FF_ 4096
#define L_  4
#define M_  128

typedef __bf16 bf16x8 __attribute__((ext_vector_type(8)));
typedef __bf16 bf16x4 __attribute__((ext_vector_type(4)));
typedef float f32x4 __attribute__((ext_vector_type(4)));

__device__ __forceinline__ void async16(const void* g, void* l) {
    __builtin_amdgcn_global_load_lds(
        (const __attribute__((address_space(1))) unsigned int*)g,
        (__attribute__((address_space(3))) unsigned int*)l, 16, 0, 0);
}

// ---------------------------------------------------------------------------
// GEMM: C[M,N] = A[M,K](bf16) @ Wt[N,K](bf16)^T + bias (+ res). BN=128, BK=32.
// BM=128: 4 waves 2x2, wave = 64x64 (4x4 16x16 subtiles).
// BM=64:  wave = 32x64 (2x4). Staging via global_load_lds w=16, XOR swizzle.
// LDS tile rows are 64B (32 bf16); chunk' = chunk ^ ((row>>1)&3) -> 2-way max.
// ---------------------------------------------------------------------------
template<int BM, typename CT>
__global__ __launch_bounds__(256) void gemm_bf16(
    const __bf16* __restrict__ A, const __bf16* __restrict__ Wt,
    const float* __restrict__ bias, const float* __restrict__ res,
    CT* __restrict__ C, int M, int N, int K)
{
    constexpr int MI = BM / 32;
    __shared__ alignas(16) __bf16 As[BM * 32];
    __shared__ alignas(16) __bf16 Bs[128 * 32];

    const int tid  = threadIdx.x;
    const int lane = tid & 63;
    const int wave = tid >> 6;
    const int wm   = wave & 1;
    const int wn   = wave >> 1;
    const int quad = lane >> 4;
    const int l16  = lane & 15;
    const int m0   = blockIdx.y * BM;
    const int n0   = blockIdx.x * 128;

    f32x4 acc[MI][4];
    #pragma unroll
    for (int i = 0; i < MI; i++)
        #pragma unroll
        for (int j = 0; j < 4; j++) acc[i][j] = (f32x4){0.f, 0.f, 0.f, 0.f};

    for (int k0 = 0; k0 < K; k0 += 32) {
        #pragma unroll
        for (int i = 0; i < BM / 64; i++) {
            int off = (i * 256 + tid) * 16;
            int row = off >> 6, chunk = (off >> 4) & 3;
            int gcol = (chunk ^ ((row >> 1) & 3)) * 8;
            async16(A + (size_t)(m0 + row) * K + k0 + gcol,
                    (char*)As + i * 4096 + wave * 1024);
        }
        #pragma unroll
        for (int i = 0; i < 2; i++) {
            int off = (i * 256 + tid) * 16;
            int row = off >> 6, chunk = (off >> 4) & 3;
            int gcol = (chunk ^ ((row >> 1) & 3)) * 8;
            async16(Wt + (size_t)(n0 + row) * K + k0 + gcol,
                    (char*)Bs + i * 4096 + wave * 1024);
        }
        __syncthreads();

        bf16x8 af[MI], bfr[4];
        #pragma unroll
        for (int mi = 0; mi < MI; mi++) {
            int r = wm * (BM / 2) + mi * 16 + l16;
            af[mi] = *(const bf16x8*)((const char*)As + r * 64 + (quad ^ ((r >> 1) & 3)) * 16);
        }
        #pragma unroll
        for (int ni = 0; ni < 4; ni++) {
            int r = wn * 64 + ni * 16 + l16;
            bfr[ni] = *(const bf16x8*)((const char*)Bs + r * 64 + (quad ^ ((r >> 1) & 3)) * 16);
        }
        #pragma unroll
        for (int mi = 0; mi < MI; mi++)
            #pragma unroll
            for (int ni = 0; ni < 4; ni++)
                acc[mi][ni] = __builtin_amdgcn_mfma_f32_16x16x32_bf16(
                    af[mi], bfr[ni], acc[mi][ni], 0, 0, 0);
        __syncthreads();
    }

    // epilogue: C/D layout col=lane&15, row=quad*4+r
    #pragma unroll
    for (int mi = 0; mi < MI; mi++) {
        #pragma unroll
        for (int ni = 0; ni < 4; ni++) {
            int col = n0 + wn * 64 + ni * 16 + l16;
            #pragma unroll
            for (int r = 0; r < 4; r++) {
                int row = m0 + wm * (BM / 2) + mi * 16 + quad * 4 + r;
                float v = acc[mi][ni][r] + bias[col];
                if (res) v += res[(size_t)row * N + col];
                C[(size_t)row * N + col] = (CT)v;
            }
        }
    }
}

// ---------------------------------------------------------------------------
// Weight transpose + cast: W[K,N] f32 -> Wt[N,K] bf16. 64x64 tiles.
// ---------------------------------------------------------------------------
__global__ __launch_bounds__(256) void transpose_w_kernel(
    const float* __restrict__ W, __bf16* __restrict__ Wt, int K, int N)
{
    __shared__ __bf16 t[64][80];
    int n0 = blockIdx.x * 64, k0 = blockIdx.y * 64;
    int tid = threadIdx.x;
    int r = tid >> 2, cb = (tid & 3) * 16;
    const float* src = W + (size_t)(k0 + r) * N + n0 + cb;
    #pragma unroll
    for (int j = 0; j < 16; j += 4) {
        f32x4 v = *(const f32x4*)(src + j);
        #pragma unroll
        for (int u = 0; u < 4; u++) t[cb + j + u][r] = (__bf16)v[u];
    }
    __syncthreads();
    __bf16* dst = Wt + (size_t)(n0 + r) * K + k0 + cb;
    *(bf16x8*)(dst)     = *(const bf16x8*)&t[r][cb];
    *(bf16x8*)(dst + 8) = *(const bf16x8*)&t[r][cb + 8];
}

// ---------------------------------------------------------------------------
// f32 -> bf16 elementwise (8 per thread)
// ---------------------------------------------------------------------------
__global__ __launch_bounds__(256) void cvt_bf16_kernel(
    const float* __restrict__ in, __bf16* __restrict__ out)
{
    size_t i = ((size_t)blockIdx.x * 256 + threadIdx.x) * 8;
    f32x4 a = *(const f32x4*)(in + i);
    f32x4 b = *(const f32x4*)(in + i + 4);
    bf16x8 o;
    #pragma unroll
    for (int u = 0; u < 4; u++) { o[u] = (__bf16)a[u]; o[4 + u] = (__bf16)b[u]; }
    *(bf16x8*)(out + i) = o;
}

// ---------------------------------------------------------------------------
// LayerNorm over D=1024, one block per row; OT = float or __bf16.
// ---------------------------------------------------------------------------
template<typename OT>
__global__ __launch_bounds__(256) void ln_kernel(
    const float* __restrict__ in,
    const float* __restrict__ g, const float* __restrict__ b,
    OT* __restrict__ out)
{
    int row = blockIdx.x;
    int t = threadIdx.x;
    __shared__ float red[256];
    __shared__ float red2[256];
    const float* ip = in + (size_t)row * D_;
    float v[4];
    float sum = 0.f, sumsq = 0.f;
    #pragma unroll
    for (int j = 0; j < 4; j++) {
        int c = t + j * 256;
        float x = ip[c];
        v[j] = x;
        sum += x; sumsq += x * x;
    }
    red[t] = sum; red2[t] = sumsq;
    __syncthreads();
    for (int s = 128; s > 0; s >>= 1) {
        if (t < s) { red[t] += red[t + s]; red2[t] += red2[t + s]; }
        __syncthreads();
    }
    float mean = red[0] * (1.0f / D_);
    float var  = red2[0] * (1.0f / D_) - mean * mean;
    float rstd = rsqrtf(var + 1e-5f);
    #pragma unroll
    for (int j = 0; j < 4; j++) {
        int c = t + j * 256;
        out[(size_t)row * D_ + c] = (OT)((v[j] - mean) * rstd * g[c] + b[c]);
    }
}

// ---------------------------------------------------------------------------
// Repack: qkv[B,T,3,H,HD] f32 -> q,k [BH][T][HD] bf16 (roped), v [BH][HD][T] bf16.
// ---------------------------------------------------------------------------
__global__ __launch_bounds__(256) void repack_kernel(
    const float* __restrict__ qkv, __bf16* __restrict__ qp,
    __bf16* __restrict__ kp, __bf16* __restrict__ vp)
{
    int bh = blockIdx.y; int h = bh & (H_ - 1); int b = bh >> 4;
    int t0 = blockIdx.x * 64;
    int tid = threadIdx.x;
    __shared__ float vt[64][65];

    int r  = tid >> 2;
    int tg = t0 + r;
    int pb = (tid & 3) * 8;
    #pragma unroll
    for (int j = 0; j < 8; j++) {
        int p = pb + j;
        int jj = (2 * p) & 31;
        float f = expf(-(float)jj * (9.210340371976184f / 32.0f)); // 10000^(-jj/32)
        float ang = (float)tg * f;
        float c = cosf(ang), s = sinf(ang);
        const float2 xq = *(const float2*)(qkv + ((size_t)(b * T_ + tg) * 3 + 0) * D_ + h * HD_ + 2 * p);
        size_t oq = ((size_t)bh * T_ + tg) * HD_ + 2 * p;
        qp[oq]     = (__bf16)(xq.x * c - xq.y * s);
        qp[oq + 1] = (__bf16)(xq.x * s + xq.y * c);
        const float2 xk = *(const float2*)(qkv + ((size_t)(b * T_ + tg) * 3 + 1) * D_ + h * HD_ + 2 * p);
        kp[oq]     = (__bf16)(xk.x * c - xk.y * s);
        kp[oq + 1] = (__bf16)(xk.x * s + xk.y * c);
    }
    {
        int cb = (tid & 3) * 16;
        const float* vsrc = qkv + ((size_t)(b * T_ + tg) * 3 + 2) * D_ + h * HD_ + cb;
        #pragma unroll
        for (int j = 0; j < 16; j += 4) {
            f32x4 v = *(const f32x4*)(vsrc + j);
            #pragma unroll
            for (int u = 0; u < 4; u++) vt[cb + j + u][r] = v[u];
        }
    }
    __syncthreads();
    {
        int d = tid >> 2, cb = (tid & 3) * 16;
        bf16x8 o0, o1;
        #pragma unroll
        for (int u = 0; u < 8; u++) { o0[u] = (__bf16)vt[d][cb + u]; o1[u] = (__bf16)vt[d][cb + 8 + u]; }
        __bf16* dst = vp + ((size_t)bh * HD_ + d) * T_ + t0 + cb;
        *(bf16x8*)(dst) = o0;
        *(bf16x8*)(dst + 8) = o1;
    }
}

// ---------------------------------------------------------------------------
// Flash MFMA attention, bf16 staging via global_load_lds + XOR swizzle.
// 64x64 bf16 tiles: 128B rows, chunk' = chunk ^ (row&7) -> 2-way max.
// grid (T/64, B*H), 256 threads.
// ---------------------------------------------------------------------------
__global__ __launch_bounds__(256) void attn_mfma_kernel(
    const __bf16* __restrict__ qp, const __bf16* __restrict__ kp,
    const __bf16* __restrict__ vp, const float* __restrict__ rb,
    __bf16* __restrict__ out)
{
    int bh = blockIdx.y; int h = bh & (H_ - 1); int b = bh >> 4;
    int q0 = blockIdx.x * 64;
    int tid = threadIdx.x;
    int lane = tid & 63, wave = tid >> 6;
    int quad = lane >> 4, l16 = lane & 15;

    __shared__ alignas(16) __bf16 Qs[64 * 64];
    __shared__ alignas(16) __bf16 Ks[64 * 64];
    __shared__ alignas(16) __bf16 Vs[64 * 64];      // [d][k]
    __shared__ __bf16 Ps[4][16][72];
    __shared__ float rbs[2 * M_ + 1];

    for (int i = tid; i < 2 * M_ + 1; i += 256) rbs[i] = rb[i * H_ + h];

    // stage Q (2 issues of 4KB)
    #pragma unroll
    for (int i = 0; i < 2; i++) {
        int off = (i * 256 + tid) * 16;
        int row = off >> 7, chunk = (off >> 4) & 7;
        int gcol = (chunk ^ (row & 7)) * 8;
        async16(qp + ((size_t)bh * T_ + q0 + row) * HD_ + gcol,
                (char*)Qs + i * 4096 + wave * 1024);
    }
    __syncthreads();

    bf16x8 qfrag[2];
    {
        int r = wave * 16 + l16;
        qfrag[0] = *(const bf16x8*)((const char*)Qs + r * 128 + ((quad)     ^ (r & 7)) * 16);
        qfrag[1] = *(const bf16x8*)((const char*)Qs + r * 128 + ((4 + quad) ^ (r & 7)) * 16);
    }

    float m_run[4], l_run[4];
    f32x4 o_acc[4];
    #pragma unroll
    for (int r2 = 0; r2 < 4; r2++) { m_run[r2] = -1e30f; l_run[r2] = 0.f; }
    #pragma unroll
    for (int ni = 0; ni < 4; ni++) o_acc[ni] = (f32x4){0.f, 0.f, 0.f, 0.f};

    const int row_l  = quad * 4;
    const int qrow_g = q0 + wave * 16 + row_l;

    for (int k0 = 0; k0 < T_; k0 += 64) {
        __syncthreads();
        #pragma unroll
        for (int i = 0; i < 2; i++) {
            int off = (i * 256 + tid) * 16;
            int row = off >> 7, chunk = (off >> 4) & 7;
            int gcol = (chunk ^ (row & 7)) * 8;
            async16(kp + ((size_t)bh * T_ + k0 + row) * HD_ + gcol,
                    (char*)Ks + i * 4096 + wave * 1024);
            async16(vp + ((size_t)bh * HD_ + row) * T_ + k0 + gcol,
                    (char*)Vs + i * 4096 + wave * 1024);
        }
        __syncthreads();

        f32x4 s_acc[4];
        #pragma unroll
        for (int ni = 0; ni < 4; ni++) s_acc[ni] = (f32x4){0.f, 0.f, 0.f, 0.f};
        #pragma unroll
        for (int ni = 0; ni < 4; ni++) {
            int r = ni * 16 + l16;
            bf16x8 kf0 = *(const bf16x8*)((const char*)Ks + r * 128 + ((quad)     ^ (r & 7)) * 16);
            bf16x8 kf1 = *(const bf16x8*)((const char*)Ks + r * 128 + ((4 + quad) ^ (r & 7)) * 16);
            s_acc[ni] = __builtin_amdgcn_mfma_f32_16x16x32_bf16(qfrag[0], kf0, s_acc[ni], 0, 0, 0);
            s_acc[ni] = __builtin_amdgcn_mfma_f32_16x16x32_bf16(qfrag[1], kf1, s_acc[ni], 0, 0, 0);
        }

        float sv[4][4];
        float rmax[4] = {-1e30f, -1e30f, -1e30f, -1e30f};
        #pragma unroll
        for (int ni = 0; ni < 4; ni++) {
            int colg = k0 + ni * 16 + l16;
            #pragma unroll
            for (int r2 = 0; r2 < 4; r2++) {
                int rel = colg - (qrow_g + r2);
                rel = (rel < -M_) ? -M_ : (rel > M_ ? M_ : rel);
                float s = s_acc[ni][r2] * 0.125f + rbs[rel + M_];
                sv[ni][r2] = s;
                rmax[r2] = fmaxf(rmax[r2], s);
            }
        }
        #pragma unroll
        for (int r2 = 0; r2 < 4; r2++)
            #pragma unroll
            for (int off = 1; off < 16; off <<= 1)
                rmax[r2] = fmaxf(rmax[r2], __shfl_xor(rmax[r2], off, 64));

        float alpha[4], rsum[4];
        #pragma unroll
        for (int r2 = 0; r2 < 4; r2++) {
            float mn = fmaxf(m_run[r2], rmax[r2]);
            alpha[r2] = __expf(m_run[r2] - mn);
            m_run[r2] = mn;
            rsum[r2] = 0.f;
        }
        #pragma unroll
        for (int ni = 0; ni < 4; ni++)
            #pragma unroll
            for (int r2 = 0; r2 < 4; r2++) {
                float p = __expf(sv[ni][r2] - m_run[r2]);
                rsum[r2] += p;
                Ps[wave][row_l + r2][ni * 16 + l16] = (__bf16)p;
            }
        #pragma unroll
        for (int r2 = 0; r2 < 4; r2++) {
            #pragma unroll
            for (int off = 1; off < 16; off <<= 1)
                rsum[r2] += __shfl_xor(rsum[r2], off, 64);
            l_run[r2] = l_run[r2] * alpha[r2] + rsum[r2];
        }
        #pragma unroll
        for (int ni = 0; ni < 4; ni++)
            #pragma unroll
            for (int r2 = 0; r2 < 4; r2++) o_acc[ni][r2] *= alpha[r2];

        #pragma unroll
        for (int kk = 0; kk < 2; kk++) {
            bf16x8 pfrag = *(const bf16x8*)&Ps[wave][l16][kk * 32 + quad * 8];
            #pragma unroll
            for (int ni = 0; ni < 4; ni++) {
                int r = ni * 16 + l16;
                bf16x8 vfrag = *(const bf16x8*)((const char*)Vs + r * 128 + ((kk * 4 + quad) ^ (r & 7)) * 16);
                o_acc[ni] = __builtin_amdgcn_mfma_f32_16x16x32_bf16(pfrag, vfrag, o_acc[ni], 0, 0, 0);
            }
        }
    }

    #pragma unroll
    for (int ni = 0; ni < 4; ni++) {
        int colg = h * HD_ + ni * 16 + l16;
        #pragma unroll
        for (int r2 = 0; r2 < 4; r2++) {
            int rowg = qrow_g + r2;
            out[(size_t)(b * T_ + rowg) * D_ + colg] = (__bf16)(o_acc[ni][r2] / l_run[r2]);
        }
    }
}

// ---------------------------------------------------------------------------
// GLU on bf16 ab[2048][8192]: cc[m][f] = a * gelu_exact(gate), bf16 out.
// ---------------------------------------------------------------------------
__global__ __launch_bounds__(256) void glu_kernel(
    const __bf16* __restrict__ ab, __bf16* __restrict__ cc)
{
    size_t i8 = (size_t)blockIdx.x * 256 + threadIdx.x;   // of 1048576
    size_t m = i8 >> 9;
    size_t fb = (i8 & 511) * 8;
    bf16x8 a8 = *(const bf16x8*)(ab + m * (2 * FF_) + fb);
    bf16x8 g8 = *(const bf16x8*)(ab + m * (2 * FF_) + FF_ + fb);
    bf16x8 o;
    #pragma unroll
    for (int u = 0; u < 8; u++) {
        float a = (float)a8[u];
        float g = (float)g8[u];
        float ge = 0.5f * g * (1.0f + erff(g * 0.7071067811865475f));
        o[u] = (__bf16)(a * ge);
    }
    *(bf16x8*)(cc + m * FF_ + fb) = o;
}

// ---------------------------------------------------------------------------
// Final: per-row norm, scale, clip, add.
// ---------------------------------------------------------------------------
__global__ __launch_bounds__(256) void final_kernel(
    const float* __restrict__ o, const float* __restrict__ alpha,
    const float* __restrict__ beta, const float* __restrict__ alpha_scale,
    const float* __restrict__ beta_scale, float* __restrict__ outp)
{
    int row = blockIdx.x;
    int t = threadIdx.x;
    __shared__ float red[256];
    const float* op = o + (size_t)row * D_;
    float v[4];
    float sumsq = 0.f;
    #pragma unroll
    for (int j = 0; j < 4; j++) {
        float x = op[t + j * 256];
        v[j] = x;
        sumsq += x * x;
    }
    red[t] = sumsq; __syncthreads();
    for (int s = 128; s > 0; s >>= 1) {
        if (t < s) red[t] += red[t + s];
        __syncthreads();
    }
    float ms = sqrtf(red[0]);
    float as = fminf(fmaxf(alpha_scale[0], 0.f), 1.f);
    float sc = 1.0f + alpha[0] * as * fminf(ms, 5.0f);
    float bb = beta[0] * beta_scale[0];
    #pragma unroll
    for (int j = 0; j < 4; j++) {
        float x = v[j] * sc + bb;
        x = fminf(fmaxf(x, -10.f), 10.f);
        outp[(size_t)row * D_ + t + j * 256] = x + v[j];
    }
}

// ---------------------------------------------------------------------------
extern "C" void kernel_launch(void* const* d_in, const int* in_sizes, int n_in,
                              void* d_out, int out_size, void* d_ws, size_t ws_size,
                              hipStream_t stream)
{
    const float* x        = (const float*)d_in[0];
    const float* context  = (const float*)d_in[1];
    const float* W_in     = (const float*)d_in[2];
    const float* b_in     = (const float*)d_in[3];
    const float* ln_in_g  = (const float*)d_in[4];
    const float* ln_in_b  = (const float*)d_in[5];
    const float* ln1_g    = (const float*)d_in[6];
    const float* ln1_b    = (const float*)d_in[7];
    const float* Wqkv     = (const float*)d_in[8];
    const float* bqkv     = (const float*)d_in[9];
    const float* Wproj    = (const float*)d_in[10];
    const float* bproj    = (const float*)d_in[11];
    const float* rel_bias = (const float*)d_in[12];
    const float* ln2_g    = (const float*)d_in[13];
    const float* ln2_b    = (const float*)d_in[14];
    const float* Wfc1     = (const float*)d_in[15];
    const float* bfc1     = (const float*)d_in[16];
    const float* Wfc2     = (const float*)d_in[17];
    const float* bfc2     = (const float*)d_in[18];
    const float* ln_f_g   = (const float*)d_in[19];
    const float* ln_f_b   = (const float*)d_in[20];
    const float* W_out    = (const float*)d_in[21];
    const float* b_out    = (const float*)d_in[22];
    const float* alpha    = (const float*)d_in[23];
    const float* beta     = (const float*)d_in[24];
    const float* alpha_s  = (const float*)d_in[25];
    const float* beta_s   = (const float*)d_in[26];

    float* ws = (float*)d_ws;
    const size_t MLN = 1024 * 1024;
    const int MROWS = B_ * T_;                           // 2048

    float*  h    = ws;                                   // 2M fl
    float*  big  = ws + 2 * MLN;                         // 8M fl (qkv f32 / ab bf16 / o f32)
    __bf16* abb  = (__bf16*)big;                         // ab as bf16 (16M elems)
    __bf16* ccb  = (__bf16*)(ws + 10 * MLN);             // 8.39M elems
    __bf16* hnb  = (__bf16*)(ws + 14 * MLN + MLN / 4);   // 2M elems
    __bf16* abuf = (__bf16*)(ws + 15 * MLN + MLN / 4);   // 2M elems (x_bf / attnout)
    __bf16* qpk  = (__bf16*)(ws + 16 * MLN + MLN / 4);   // 2M elems
    __bf16* kpk  = (__bf16*)(ws + 17 * MLN + MLN / 4);   // 2M elems
    __bf16* vpk  = (__bf16*)(ws + 18 * MLN + MLN / 4);   // 2M elems
    __bf16* wtb  = (__bf16*)(ws + 19 * MLN + MLN / 4);   // 16M elems (32MB)
    __bf16* wt_qkv  = wtb;                               // 3.146M
    __bf16* wt_proj = wtb + 3145728;                     // 1.049M
    __bf16* wt_fc1  = wtb + 4194304;                     // 8.389M
    __bf16* wt_fc2  = wtb + 12582912;                    // 4.194M

    dim3 blk(256);

    // x -> bf16; W_in transpose; in-proj + context; LN
    cvt_bf16_kernel<<<dim3(1024), blk, 0, stream>>>(x, abuf);
    transpose_w_kernel<<<dim3(16, 16), blk, 0, stream>>>(W_in, wtb, D_, D_);
    gemm_bf16<64, float><<<dim3(8, 32), blk, 0, stream>>>(abuf, wtb, b_in, context, big,
                                                          MROWS, D_, D_);
    ln_kernel<float><<<dim3(MROWS), blk, 0, stream>>>(big, ln_in_g, ln_in_b, h);

    for (int l = 0; l < L_; l++) {
        const float* wqkv = Wqkv + (size_t)l * D_ * 3 * D_;
        const float* bq   = bqkv + (size_t)l * 3 * D_;
        const float* wp   = Wproj + (size_t)l * D_ * D_;
        const float* bp   = bproj + (size_t)l * D_;
        const float* rb   = rel_bias + (size_t)l * (2 * M_ + 1) * H_;
        const float* w1   = Wfc1 + (size_t)l * D_ * 2 * FF_;
        const float* bf1  = bfc1 + (size_t)l * 2 * FF_;
        const float* w2   = Wfc2 + (size_t)l * FF_ * D_;
        const float* bf2  = bfc2 + (size_t)l * D_;

        transpose_w_kernel<<<dim3(48, 16),  blk, 0, stream>>>(wqkv, wt_qkv, D_, 3 * D_);
        transpose_w_kernel<<<dim3(16, 16),  blk, 0, stream>>>(wp,   wt_proj, D_, D_);
        transpose_w_kernel<<<dim3(128, 16), blk, 0, stream>>>(w1,   wt_fc1, D_, 2 * FF_);
        transpose_w_kernel<<<dim3(16, 64),  blk, 0, stream>>>(w2,   wt_fc2, FF_, D_);

        ln_kernel<__bf16><<<dim3(MROWS), blk, 0, stream>>>(h, ln1_g + l * D_, ln1_b + l * D_, hnb);
        gemm_bf16<128, float><<<dim3(24, 16), blk, 0, stream>>>(hnb, wt_qkv, bq, nullptr, big,
                                                                MROWS, 3 * D_, D_);
        repack_kernel<<<dim3(T_ / 64, B_ * H_), blk, 0, stream>>>(big, qpk, kpk, vpk);
        attn_mfma_kernel<<<dim3(T_ / 64, B_ * H_), blk, 0, stream>>>(qpk, kpk, vpk, rb, abuf);
        gemm_bf16<64, float><<<dim3(8, 32), blk, 0, stream>>>(abuf, wt_proj, bp, h, h,
                                                              MROWS, D_, D_);
        ln_kernel<__bf16><<<dim3(MROWS), blk, 0, stream>>>(h, ln2_g + l * D_, ln2_b + l * D_, hnb);
        gemm_bf16<128, __bf16><<<dim3(64, 16), blk, 0, stream>>>(hnb, wt_fc1, bf1, nullptr, abb,
                                                                 MROWS, 2 * FF_, D_);
        glu_kernel<<<dim3(4096), blk, 0, stream>>>(abb, ccb);
        gemm_bf16<64, float><<<dim3(8, 32), blk, 0, stream>>>(ccb, wt_fc2, bf2, h, h,
                                                              MROWS, D_, FF_);
    }

    ln_kernel<__bf16><<<dim3(MROWS), blk, 0, stream>>>(h, ln_f_g, ln_f_b, hnb);
    transpose_w_kernel<<<dim3(16, 16), blk, 0, stream>>>(W_out, wtb, D_, D_);
    gemm_bf16<64, float><<<dim3(8, 32), blk, 0, stream>>>(hnb, wtb, b_out, nullptr, big,
                                                          MROWS, D_, D_);
    final_kernel<<<dim3(MROWS), blk, 0, stream>>>(big, alpha, beta, alpha_s, beta_s,
                                                  (float*)d_out);
}

// Round 4
// 1213.328 us; speedup vs baseline: 7.5579x; 1.1950x over previous
//
#include <hip/hip_runtime.h>
#include <cmath>

#define B_  2
#define T_  1024
#define D_  1024
#define H_  16
#define HD_ 64
#define FF_ 4096
#define L_  4
#define M_  128

typedef __bf16 bf16x8 __attribute__((ext_vector_type(8)));
typedef __bf16 bf16x4 __attribute__((ext_vector_type(4)));
typedef float f32x4 __attribute__((ext_vector_type(4)));

__device__ __forceinline__ void async16(const void* g, void* l) {
    __builtin_amdgcn_global_load_lds(
        (const __attribute__((address_space(1))) unsigned int*)g,
        (__attribute__((address_space(3))) unsigned int*)l, 16, 0, 0);
}

// ---------------------------------------------------------------------------
// GEMM: C[M,N] = A[M,K](bf16) @ Wt[N,K](bf16)^T + bias (+res). BK=64.
// LDS rows are 128B (64 bf16) = 8 chunks of 16B; chunk' = chunk ^ (row&7)
// -> ds_read_b128 2-way max (free), global_load_lds lane-linear.
// 4 waves: wm=wave&1 (rows), wn=wave>>1 (cols). Wave tile = BM/2 x BN/2.
// ---------------------------------------------------------------------------
template<int BM, int BN, typename CT>
__global__ __launch_bounds__(256) void gemm_bf16(
    const __bf16* __restrict__ A, const __bf16* __restrict__ Wt,
    const float* __restrict__ bias, const float* __restrict__ res,
    CT* __restrict__ C, int M, int N, int K)
{
    constexpr int MI = BM / 32;
    constexpr int NI = BN / 32;
    __shared__ alignas(16) __bf16 As[BM * 64];
    __shared__ alignas(16) __bf16 Bs[BN * 64];

    const int tid  = threadIdx.x;
    const int lane = tid & 63;
    const int wave = tid >> 6;
    const int wm   = wave & 1;
    const int wn   = wave >> 1;
    const int quad = lane >> 4;
    const int l16  = lane & 15;
    const int m0   = blockIdx.y * BM;
    const int n0   = blockIdx.x * BN;

    f32x4 acc[MI][NI];
    #pragma unroll
    for (int i = 0; i < MI; i++)
        #pragma unroll
        for (int j = 0; j < NI; j++) acc[i][j] = (f32x4){0.f, 0.f, 0.f, 0.f};

    for (int k0 = 0; k0 < K; k0 += 64) {
        #pragma unroll
        for (int i = 0; i < BM / 32; i++) {
            int off = (i * 256 + tid) * 16;
            int row = off >> 7, chunk = (off >> 4) & 7;
            int gcol = (chunk ^ (row & 7)) * 8;
            async16(A + (size_t)(m0 + row) * K + k0 + gcol,
                    (char*)As + i * 4096 + wave * 1024);
        }
        #pragma unroll
        for (int i = 0; i < BN / 32; i++) {
            int off = (i * 256 + tid) * 16;
            int row = off >> 7, chunk = (off >> 4) & 7;
            int gcol = (chunk ^ (row & 7)) * 8;
            async16(Wt + (size_t)(n0 + row) * K + k0 + gcol,
                    (char*)Bs + i * 4096 + wave * 1024);
        }
        __syncthreads();

        bf16x8 af[MI][2], bfr[NI][2];
        #pragma unroll
        for (int mi = 0; mi < MI; mi++) {
            int r = wm * (BM / 2) + mi * 16 + l16;
            #pragma unroll
            for (int kk = 0; kk < 2; kk++) {
                int c = kk * 4 + quad;
                af[mi][kk] = *(const bf16x8*)((const char*)As + r * 128 + ((c ^ (r & 7)) * 16));
            }
        }
        #pragma unroll
        for (int ni = 0; ni < NI; ni++) {
            int r = wn * (BN / 2) + ni * 16 + l16;
            #pragma unroll
            for (int kk = 0; kk < 2; kk++) {
                int c = kk * 4 + quad;
                bfr[ni][kk] = *(const bf16x8*)((const char*)Bs + r * 128 + ((c ^ (r & 7)) * 16));
            }
        }
        #pragma unroll
        for (int kk = 0; kk < 2; kk++)
            #pragma unroll
            for (int mi = 0; mi < MI; mi++)
                #pragma unroll
                for (int ni = 0; ni < NI; ni++)
                    acc[mi][ni] = __builtin_amdgcn_mfma_f32_16x16x32_bf16(
                        af[mi][kk], bfr[ni][kk], acc[mi][ni], 0, 0, 0);
        __syncthreads();
    }

    #pragma unroll
    for (int mi = 0; mi < MI; mi++) {
        #pragma unroll
        for (int ni = 0; ni < NI; ni++) {
            int col = n0 + wn * (BN / 2) + ni * 16 + l16;
            #pragma unroll
            for (int r = 0; r < 4; r++) {
                int row = m0 + wm * (BM / 2) + mi * 16 + quad * 4 + r;
                float v = acc[mi][ni][r] + bias[col];
                if (res) v += res[(size_t)row * N + col];
                C[(size_t)row * N + col] = (CT)v;
            }
        }
    }
}

// ---------------------------------------------------------------------------
// Fused fc1 + GLU: block computes cols [n0,n0+128) of 'a' AND of 'gate'
// (gate at FF+n0 in Wt/bias), writes cc = a * gelu_exact(gate) bf16.
// BM=64, BN=128, K=D. grid (FF/128, M/64).
// ---------------------------------------------------------------------------
__global__ __launch_bounds__(256) void fc1_glu_kernel(
    const __bf16* __restrict__ A, const __bf16* __restrict__ Wt,
    const float* __restrict__ bias, __bf16* __restrict__ cc, int K)
{
    __shared__ alignas(16) __bf16 As[64 * 64];
    __shared__ alignas(16) __bf16 Bs[128 * 64];
    __shared__ alignas(16) __bf16 Gs[128 * 64];

    const int tid  = threadIdx.x;
    const int lane = tid & 63;
    const int wave = tid >> 6;
    const int wm   = wave & 1;
    const int wn   = wave >> 1;
    const int quad = lane >> 4;
    const int l16  = lane & 15;
    const int m0   = blockIdx.y * 64;
    const int n0   = blockIdx.x * 128;

    f32x4 acc_a[2][4], acc_g[2][4];
    #pragma unroll
    for (int i = 0; i < 2; i++)
        #pragma unroll
        for (int j = 0; j < 4; j++) {
            acc_a[i][j] = (f32x4){0.f, 0.f, 0.f, 0.f};
            acc_g[i][j] = (f32x4){0.f, 0.f, 0.f, 0.f};
        }

    for (int k0 = 0; k0 < K; k0 += 64) {
        #pragma unroll
        for (int i = 0; i < 2; i++) {
            int off = (i * 256 + tid) * 16;
            int row = off >> 7, chunk = (off >> 4) & 7;
            int gcol = (chunk ^ (row & 7)) * 8;
            async16(A + (size_t)(m0 + row) * K + k0 + gcol,
                    (char*)As + i * 4096 + wave * 1024);
        }
        #pragma unroll
        for (int i = 0; i < 4; i++) {
            int off = (i * 256 + tid) * 16;
            int row = off >> 7, chunk = (off >> 4) & 7;
            int gcol = (chunk ^ (row & 7)) * 8;
            async16(Wt + (size_t)(n0 + row) * K + k0 + gcol,
                    (char*)Bs + i * 4096 + wave * 1024);
            async16(Wt + (size_t)(FF_ + n0 + row) * K + k0 + gcol,
                    (char*)Gs + i * 4096 + wave * 1024);
        }
        __syncthreads();

        bf16x8 af[2][2];
        #pragma unroll
        for (int mi = 0; mi < 2; mi++) {
            int r = wm * 32 + mi * 16 + l16;
            #pragma unroll
            for (int kk = 0; kk < 2; kk++) {
                int c = kk * 4 + quad;
                af[mi][kk] = *(const bf16x8*)((const char*)As + r * 128 + ((c ^ (r & 7)) * 16));
            }
        }
        #pragma unroll
        for (int kk = 0; kk < 2; kk++) {
            #pragma unroll
            for (int ni = 0; ni < 4; ni++) {
                int r = wn * 64 + ni * 16 + l16;
                int c = kk * 4 + quad;
                bf16x8 b1 = *(const bf16x8*)((const char*)Bs + r * 128 + ((c ^ (r & 7)) * 16));
                bf16x8 b2 = *(const bf16x8*)((const char*)Gs + r * 128 + ((c ^ (r & 7)) * 16));
                #pragma unroll
                for (int mi = 0; mi < 2; mi++) {
                    acc_a[mi][ni] = __builtin_amdgcn_mfma_f32_16x16x32_bf16(
                        af[mi][kk], b1, acc_a[mi][ni], 0, 0, 0);
                    acc_g[mi][ni] = __builtin_amdgcn_mfma_f32_16x16x32_bf16(
                        af[mi][kk], b2, acc_g[mi][ni], 0, 0, 0);
                }
            }
        }
        __syncthreads();
    }

    #pragma unroll
    for (int mi = 0; mi < 2; mi++) {
        #pragma unroll
        for (int ni = 0; ni < 4; ni++) {
            int col = n0 + wn * 64 + ni * 16 + l16;
            float ba = bias[col], bg = bias[FF_ + col];
            #pragma unroll
            for (int r = 0; r < 4; r++) {
                int row = m0 + wm * 32 + mi * 16 + quad * 4 + r;
                float a = acc_a[mi][ni][r] + ba;
                float g = acc_g[mi][ni][r] + bg;
                float ge = 0.5f * g * (1.0f + erff(g * 0.7071067811865475f));
                cc[(size_t)row * FF_ + col] = (__bf16)(a * ge);
            }
        }
    }
}

// ---------------------------------------------------------------------------
// Weight transpose + cast: W[K,N] f32 -> Wt[N,K] bf16. 64x64 tiles.
// blockIdx.z = layer: src stride K*N, dst stride dstride.
// ---------------------------------------------------------------------------
__global__ __launch_bounds__(256) void transpose_w_kernel(
    const float* __restrict__ W, __bf16* __restrict__ Wt, int K, int N,
    size_t dstride)
{
    W  += (size_t)blockIdx.z * K * N;
    Wt += (size_t)blockIdx.z * dstride;
    __shared__ __bf16 t[64][80];
    int n0 = blockIdx.x * 64, k0 = blockIdx.y * 64;
    int tid = threadIdx.x;
    int r = tid >> 2, cb = (tid & 3) * 16;
    const float* src = W + (size_t)(k0 + r) * N + n0 + cb;
    #pragma unroll
    for (int j = 0; j < 16; j += 4) {
        f32x4 v = *(const f32x4*)(src + j);
        #pragma unroll
        for (int u = 0; u < 4; u++) t[cb + j + u][r] = (__bf16)v[u];
    }
    __syncthreads();
    __bf16* dst = Wt + (size_t)(n0 + r) * K + k0 + cb;
    *(bf16x8*)(dst)     = *(const bf16x8*)&t[r][cb];
    *(bf16x8*)(dst + 8) = *(const bf16x8*)&t[r][cb + 8];
}

// ---------------------------------------------------------------------------
__global__ __launch_bounds__(256) void cvt_bf16_kernel(
    const float* __restrict__ in, __bf16* __restrict__ out)
{
    size_t i = ((size_t)blockIdx.x * 256 + threadIdx.x) * 8;
    f32x4 a = *(const f32x4*)(in + i);
    f32x4 b = *(const f32x4*)(in + i + 4);
    bf16x8 o;
    #pragma unroll
    for (int u = 0; u < 4; u++) { o[u] = (__bf16)a[u]; o[4 + u] = (__bf16)b[u]; }
    *(bf16x8*)(out + i) = o;
}

// ---------------------------------------------------------------------------
template<typename OT>
__global__ __launch_bounds__(256) void ln_kernel(
    const float* __restrict__ in,
    const float* __restrict__ g, const float* __restrict__ b,
    OT* __restrict__ out)
{
    int row = blockIdx.x;
    int t = threadIdx.x;
    __shared__ float red[256];
    __shared__ float red2[256];
    const float* ip = in + (size_t)row * D_;
    float v[4];
    float sum = 0.f, sumsq = 0.f;
    #pragma unroll
    for (int j = 0; j < 4; j++) {
        int c = t + j * 256;
        float x = ip[c];
        v[j] = x;
        sum += x; sumsq += x * x;
    }
    red[t] = sum; red2[t] = sumsq;
    __syncthreads();
    for (int s = 128; s > 0; s >>= 1) {
        if (t < s) { red[t] += red[t + s]; red2[t] += red2[t + s]; }
        __syncthreads();
    }
    float mean = red[0] * (1.0f / D_);
    float var  = red2[0] * (1.0f / D_) - mean * mean;
    float rstd = rsqrtf(var + 1e-5f);
    #pragma unroll
    for (int j = 0; j < 4; j++) {
        int c = t + j * 256;
        out[(size_t)row * D_ + c] = (OT)((v[j] - mean) * rstd * g[c] + b[c]);
    }
}

// ---------------------------------------------------------------------------
// Repack: qkv[B,T,3,H,HD] bf16 -> q,k [BH][T][HD] (roped), v [BH][HD][T].
// grid (T/64, B*H), 256 threads.
// ---------------------------------------------------------------------------
__global__ __launch_bounds__(256) void repack_kernel(
    const __bf16* __restrict__ qkv, __bf16* __restrict__ qp,
    __bf16* __restrict__ kp, __bf16* __restrict__ vp)
{
    int bh = blockIdx.y; int h = bh & (H_ - 1); int b = bh >> 4;
    int t0 = blockIdx.x * 64;
    int tid = threadIdx.x;
    __shared__ __bf16 vt[64][72];

    int r  = tid >> 2;
    int tg = t0 + r;
    int cb = (tid & 3) * 16;       // element base within HD (8 pairs)

    const __bf16* qsrc = qkv + ((size_t)(b * T_ + tg) * 3 + 0) * D_ + h * HD_ + cb;
    const __bf16* ksrc = qkv + ((size_t)(b * T_ + tg) * 3 + 1) * D_ + h * HD_ + cb;
    bf16x8 q0 = *(const bf16x8*)qsrc,  q1 = *(const bf16x8*)(qsrc + 8);
    bf16x8 k0 = *(const bf16x8*)ksrc,  k1 = *(const bf16x8*)(ksrc + 8);
    bf16x8 qo0, qo1, ko0, ko1;
    #pragma unroll
    for (int p = 0; p < 8; p++) {
        int pg = (cb >> 1) + p;               // global pair index 0..31
        int jj = (2 * pg) & 31;
        float f = expf(-(float)jj * (9.210340371976184f / 32.0f));
        float ang = (float)tg * f;
        float c = cosf(ang), s = sinf(ang);
        float qe, qo, ke, ko;
        if (p < 4) { qe = (float)q0[2*p]; qo = (float)q0[2*p+1]; ke = (float)k0[2*p]; ko = (float)k0[2*p+1]; }
        else       { qe = (float)q1[2*(p-4)]; qo = (float)q1[2*(p-4)+1]; ke = (float)k1[2*(p-4)]; ko = (float)k1[2*(p-4)+1]; }
        float a0 = qe * c - qo * s, a1 = qe * s + qo * c;
        float b0 = ke * c - ko * s, b1 = ke * s + ko * c;
        if (p < 4) { qo0[2*p] = (__bf16)a0; qo0[2*p+1] = (__bf16)a1; ko0[2*p] = (__bf16)b0; ko0[2*p+1] = (__bf16)b1; }
        else       { qo1[2*(p-4)] = (__bf16)a0; qo1[2*(p-4)+1] = (__bf16)a1; ko1[2*(p-4)] = (__bf16)b0; ko1[2*(p-4)+1] = (__bf16)b1; }
    }
    size_t odst = ((size_t)bh * T_ + tg) * HD_ + cb;
    *(bf16x8*)(qp + odst) = qo0; *(bf16x8*)(qp + odst + 8) = qo1;
    *(bf16x8*)(kp + odst) = ko0; *(bf16x8*)(kp + odst + 8) = ko1;

    // v transpose
    {
        const __bf16* vsrc = qkv + ((size_t)(b * T_ + tg) * 3 + 2) * D_ + h * HD_ + cb;
        bf16x8 v0 = *(const bf16x8*)vsrc, v1 = *(const bf16x8*)(vsrc + 8);
        #pragma unroll
        for (int u = 0; u < 8; u++) { vt[cb + u][r] = v0[u]; vt[cb + 8 + u][r] = v1[u]; }
    }
    __syncthreads();
    {
        int d = tid >> 2, cb2 = (tid & 3) * 16;
        bf16x8 o0, o1;
        #pragma unroll
        for (int u = 0; u < 8; u++) { o0[u] = vt[d][cb2 + u]; o1[u] = vt[d][cb2 + 8 + u]; }
        __bf16* dst = vp + ((size_t)bh * HD_ + d) * T_ + t0 + cb2;
        *(bf16x8*)(dst) = o0;
        *(bf16x8*)(dst + 8) = o1;
    }
}

// ---------------------------------------------------------------------------
// Flash MFMA attention (unchanged from R3 — verified working).
// ---------------------------------------------------------------------------
__global__ __launch_bounds__(256) void attn_mfma_kernel(
    const __bf16* __restrict__ qp, const __bf16* __restrict__ kp,
    const __bf16* __restrict__ vp, const float* __restrict__ rb,
    __bf16* __restrict__ out)
{
    int bh = blockIdx.y; int h = bh & (H_ - 1); int b = bh >> 4;
    int q0 = blockIdx.x * 64;
    int tid = threadIdx.x;
    int lane = tid & 63, wave = tid >> 6;
    int quad = lane >> 4, l16 = lane & 15;

    __shared__ alignas(16) __bf16 Qs[64 * 64];
    __shared__ alignas(16) __bf16 Ks[64 * 64];
    __shared__ alignas(16) __bf16 Vs[64 * 64];
    __shared__ __bf16 Ps[4][16][72];
    __shared__ float rbs[2 * M_ + 1];

    for (int i = tid; i < 2 * M_ + 1; i += 256) rbs[i] = rb[i * H_ + h];

    #pragma unroll
    for (int i = 0; i < 2; i++) {
        int off = (i * 256 + tid) * 16;
        int row = off >> 7, chunk = (off >> 4) & 7;
        int gcol = (chunk ^ (row & 7)) * 8;
        async16(qp + ((size_t)bh * T_ + q0 + row) * HD_ + gcol,
                (char*)Qs + i * 4096 + wave * 1024);
    }
    __syncthreads();

    bf16x8 qfrag[2];
    {
        int r = wave * 16 + l16;
        qfrag[0] = *(const bf16x8*)((const char*)Qs + r * 128 + ((quad)     ^ (r & 7)) * 16);
        qfrag[1] = *(const bf16x8*)((const char*)Qs + r * 128 + ((4 + quad) ^ (r & 7)) * 16);
    }

    float m_run[4], l_run[4];
    f32x4 o_acc[4];
    #pragma unroll
    for (int r2 = 0; r2 < 4; r2++) { m_run[r2] = -1e30f; l_run[r2] = 0.f; }
    #pragma unroll
    for (int ni = 0; ni < 4; ni++) o_acc[ni] = (f32x4){0.f, 0.f, 0.f, 0.f};

    const int row_l  = quad * 4;
    const int qrow_g = q0 + wave * 16 + row_l;

    for (int k0 = 0; k0 < T_; k0 += 64) {
        __syncthreads();
        #pragma unroll
        for (int i = 0; i < 2; i++) {
            int off = (i * 256 + tid) * 16;
            int row = off >> 7, chunk = (off >> 4) & 7;
            int gcol = (chunk ^ (row & 7)) * 8;
            async16(kp + ((size_t)bh * T_ + k0 + row) * HD_ + gcol,
                    (char*)Ks + i * 4096 + wave * 1024);
            async16(vp + ((size_t)bh * HD_ + row) * T_ + k0 + gcol,
                    (char*)Vs + i * 4096 + wave * 1024);
        }
        __syncthreads();

        f32x4 s_acc[4];
        #pragma unroll
        for (int ni = 0; ni < 4; ni++) s_acc[ni] = (f32x4){0.f, 0.f, 0.f, 0.f};
        #pragma unroll
        for (int ni = 0; ni < 4; ni++) {
            int r = ni * 16 + l16;
            bf16x8 kf0 = *(const bf16x8*)((const char*)Ks + r * 128 + ((quad)     ^ (r & 7)) * 16);
            bf16x8 kf1 = *(const bf16x8*)((const char*)Ks + r * 128 + ((4 + quad) ^ (r & 7)) * 16);
            s_acc[ni] = __builtin_amdgcn_mfma_f32_16x16x32_bf16(qfrag[0], kf0, s_acc[ni], 0, 0, 0);
            s_acc[ni] = __builtin_amdgcn_mfma_f32_16x16x32_bf16(qfrag[1], kf1, s_acc[ni], 0, 0, 0);
        }

        float sv[4][4];
        float rmax[4] = {-1e30f, -1e30f, -1e30f, -1e30f};
        #pragma unroll
        for (int ni = 0; ni < 4; ni++) {
            int colg = k0 + ni * 16 + l16;
            #pragma unroll
            for (int r2 = 0; r2 < 4; r2++) {
                int rel = colg - (qrow_g + r2);
                rel = (rel < -M_) ? -M_ : (rel > M_ ? M_ : rel);
                float s = s_acc[ni][r2] * 0.125f + rbs[rel + M_];
                sv[ni][r2] = s;
                rmax[r2] = fmaxf(rmax[r2], s);
            }
        }
        #pragma unroll
        for (int r2 = 0; r2 < 4; r2++)
            #pragma unroll
            for (int off = 1; off < 16; off <<= 1)
                rmax[r2] = fmaxf(rmax[r2], __shfl_xor(rmax[r2], off, 64));

        float alpha[4], rsum[4];
        #pragma unroll
        for (int r2 = 0; r2 < 4; r2++) {
            float mn = fmaxf(m_run[r2], rmax[r2]);
            alpha[r2] = __expf(m_run[r2] - mn);
            m_run[r2] = mn;
            rsum[r2] = 0.f;
        }
        #pragma unroll
        for (int ni = 0; ni < 4; ni++)
            #pragma unroll
            for (int r2 = 0; r2 < 4; r2++) {
                float p = __expf(sv[ni][r2] - m_run[r2]);
                rsum[r2] += p;
                Ps[wave][row_l + r2][ni * 16 + l16] = (__bf16)p;
            }
        #pragma unroll
        for (int r2 = 0; r2 < 4; r2++) {
            #pragma unroll
            for (int off = 1; off < 16; off <<= 1)
                rsum[r2] += __shfl_xor(rsum[r2], off, 64);
            l_run[r2] = l_run[r2] * alpha[r2] + rsum[r2];
        }
        #pragma unroll
        for (int ni = 0; ni < 4; ni++)
            #pragma unroll
            for (int r2 = 0; r2 < 4; r2++) o_acc[ni][r2] *= alpha[r2];

        #pragma unroll
        for (int kk = 0; kk < 2; kk++) {
            bf16x8 pfrag = *(const bf16x8*)&Ps[wave][l16][kk * 32 + quad * 8];
            #pragma unroll
            for (int ni = 0; ni < 4; ni++) {
                int r = ni * 16 + l16;
                bf16x8 vfrag = *(const bf16x8*)((const char*)Vs + r * 128 + ((kk * 4 + quad) ^ (r & 7)) * 16);
                o_acc[ni] = __builtin_amdgcn_mfma_f32_16x16x32_bf16(pfrag, vfrag, o_acc[ni], 0, 0, 0);
            }
        }
    }

    #pragma unroll
    for (int ni = 0; ni < 4; ni++) {
        int colg = h * HD_ + ni * 16 + l16;
        #pragma unroll
        for (int r2 = 0; r2 < 4; r2++) {
            int rowg = qrow_g + r2;
            out[(size_t)(b * T_ + rowg) * D_ + colg] = (__bf16)(o_acc[ni][r2] / l_run[r2]);
        }
    }
}

// ---------------------------------------------------------------------------
__global__ __launch_bounds__(256) void final_kernel(
    const float* __restrict__ o, const float* __restrict__ alpha,
    const float* __restrict__ beta, const float* __restrict__ alpha_scale,
    const float* __restrict__ beta_scale, float* __restrict__ outp)
{
    int row = blockIdx.x;
    int t = threadIdx.x;
    __shared__ float red[256];
    const float* op = o + (size_t)row * D_;
    float v[4];
    float sumsq = 0.f;
    #pragma unroll
    for (int j = 0; j < 4; j++) {
        float x = op[t + j * 256];
        v[j] = x;
        sumsq += x * x;
    }
    red[t] = sumsq; __syncthreads();
    for (int s = 128; s > 0; s >>= 1) {
        if (t < s) red[t] += red[t + s];
        __syncthreads();
    }
    float ms = sqrtf(red[0]);
    float as = fminf(fmaxf(alpha_scale[0], 0.f), 1.f);
    float sc = 1.0f + alpha[0] * as * fminf(ms, 5.0f);
    float bb = beta[0] * beta_scale[0];
    #pragma unroll
    for (int j = 0; j < 4; j++) {
        float x = v[j] * sc + bb;
        x = fminf(fmaxf(x, -10.f), 10.f);
        outp[(size_t)row * D_ + t + j * 256] = x + v[j];
    }
}

// ---------------------------------------------------------------------------
extern "C" void kernel_launch(void* const* d_in, const int* in_sizes, int n_in,
                              void* d_out, int out_size, void* d_ws, size_t ws_size,
                              hipStream_t stream)
{
    const float* x        = (const float*)d_in[0];
    const float* context  = (const float*)d_in[1];
    const float* W_in     = (const float*)d_in[2];
    const float* b_in     = (const float*)d_in[3];
    const float* ln_in_g  = (const float*)d_in[4];
    const float* ln_in_b  = (const float*)d_in[5];
    const float* ln1_g    = (const float*)d_in[6];
    const float* ln1_b    = (const float*)d_in[7];
    const float* Wqkv     = (const float*)d_in[8];
    const float* bqkv     = (const float*)d_in[9];
    const float* Wproj    = (const float*)d_in[10];
    const float* bproj    = (const float*)d_in[11];
    const float* rel_bias = (const float*)d_in[12];
    const float* ln2_g    = (const float*)d_in[13];
    const float* ln2_b    = (const float*)d_in[14];
    const float* Wfc1     = (const float*)d_in[15];
    const float* bfc1     = (const float*)d_in[16];
    const float* Wfc2     = (const float*)d_in[17];
    const float* bfc2     = (const float*)d_in[18];
    const float* ln_f_g   = (const float*)d_in[19];
    const float* ln_f_b   = (const float*)d_in[20];
    const float* W_out    = (const float*)d_in[21];
    const float* b_out    = (const float*)d_in[22];
    const float* alpha    = (const float*)d_in[23];
    const float* beta     = (const float*)d_in[24];
    const float* alpha_s  = (const float*)d_in[25];
    const float* beta_s   = (const float*)d_in[26];

    float* ws = (float*)d_ws;
    const size_t MLN = 1024 * 1024;
    const int MROWS = B_ * T_;                            // 2048

    float*  h    = ws;                                    // [0, 2M) f32
    __bf16* hnb  = (__bf16*)(ws + 2 * MLN);               // 2M bf16
    __bf16* abuf = (__bf16*)(ws + 3 * MLN);               // 2M bf16 (x_bf / attnout)
    __bf16* qpk  = (__bf16*)(ws + 4 * MLN);
    __bf16* kpk  = (__bf16*)(ws + 5 * MLN);
    __bf16* vpk  = (__bf16*)(ws + 6 * MLN);
    __bf16* qkvb = (__bf16*)(ws + 8 * MLN);               // 6.29M bf16
    __bf16* ccb  = (__bf16*)(ws + 12 * MLN);              // 8.39M bf16
    float*  tmpf = ws + 17 * MLN;                         // 2M f32 (in/out proj out)
    __bf16* wtb  = (__bf16*)(ws + 19 * MLN);              // transposed weights

    __bf16* wt_in  = wtb;
    __bf16* wt_out = wtb + 1048576;
    const size_t LSTRIDE = 16777216;
    __bf16* wt_qkv0  = wtb + 2097152;
    __bf16* wt_proj0 = wt_qkv0 + 3145728;
    __bf16* wt_fc10  = wt_qkv0 + 4194304;
    __bf16* wt_fc20  = wt_qkv0 + 12582912;

    dim3 blk(256);

    // --- all weight transposes up front ---
    transpose_w_kernel<<<dim3(16, 16, 1),  blk, 0, stream>>>(W_in,  wt_in,  D_, D_, 0);
    transpose_w_kernel<<<dim3(16, 16, 1),  blk, 0, stream>>>(W_out, wt_out, D_, D_, 0);
    transpose_w_kernel<<<dim3(48, 16, 4),  blk, 0, stream>>>(Wqkv,  wt_qkv0,  D_, 3 * D_, LSTRIDE);
    transpose_w_kernel<<<dim3(16, 16, 4),  blk, 0, stream>>>(Wproj, wt_proj0, D_, D_, LSTRIDE);
    transpose_w_kernel<<<dim3(128, 16, 4), blk, 0, stream>>>(Wfc1,  wt_fc10,  D_, 2 * FF_, LSTRIDE);
    transpose_w_kernel<<<dim3(16, 64, 4),  blk, 0, stream>>>(Wfc2,  wt_fc20,  FF_, D_, LSTRIDE);

    // --- input projection + LN ---
    cvt_bf16_kernel<<<dim3(1024), blk, 0, stream>>>(x, abuf);
    gemm_bf16<64, 64, float><<<dim3(16, 32), blk, 0, stream>>>(abuf, wt_in, b_in, context,
                                                               tmpf, MROWS, D_, D_);
    ln_kernel<float><<<dim3(MROWS), blk, 0, stream>>>(tmpf, ln_in_g, ln_in_b, h);

    for (int l = 0; l < L_; l++) {
        const float* bq   = bqkv + (size_t)l * 3 * D_;
        const float* bp   = bproj + (size_t)l * D_;
        const float* rb   = rel_bias + (size_t)l * (2 * M_ + 1) * H_;
        const float* bf1  = bfc1 + (size_t)l * 2 * FF_;
        const float* bf2  = bfc2 + (size_t)l * D_;
        __bf16* wt_qkv  = wt_qkv0  + (size_t)l * LSTRIDE;
        __bf16* wt_proj = wt_proj0 + (size_t)l * LSTRIDE;
        __bf16* wt_fc1  = wt_fc10  + (size_t)l * LSTRIDE;
        __bf16* wt_fc2  = wt_fc20  + (size_t)l * LSTRIDE;

        ln_kernel<__bf16><<<dim3(MROWS), blk, 0, stream>>>(h, ln1_g + l * D_, ln1_b + l * D_, hnb);
        gemm_bf16<64, 128, __bf16><<<dim3(24, 32), blk, 0, stream>>>(hnb, wt_qkv, bq, nullptr,
                                                                     qkvb, MROWS, 3 * D_, D_);
        repack_kernel<<<dim3(T_ / 64, B_ * H_), blk, 0, stream>>>(qkvb, qpk, kpk, vpk);
        attn_mfma_kernel<<<dim3(T_ / 64, B_ * H_), blk, 0, stream>>>(qpk, kpk, vpk, rb, abuf);
        gemm_bf16<64, 64, float><<<dim3(16, 32), blk, 0, stream>>>(abuf, wt_proj, bp, h, h,
                                                                   MROWS, D_, D_);
        ln_kernel<__bf16><<<dim3(MROWS), blk, 0, stream>>>(h, ln2_g + l * D_, ln2_b + l * D_, hnb);
        fc1_glu_kernel<<<dim3(32, 32), blk, 0, stream>>>(hnb, wt_fc1, bf1, ccb, D_);
        gemm_bf16<64, 64, float><<<dim3(16, 32), blk, 0, stream>>>(ccb, wt_fc2, bf2, h, h,
                                                                   MROWS, D_, FF_);
    }

    ln_kernel<__bf16><<<dim3(MROWS), blk, 0, stream>>>(h, ln_f_g, ln_f_b, hnb);
    gemm_bf16<64, 64, float><<<dim3(16, 32), blk, 0, stream>>>(hnb, wt_out, b_out, nullptr,
                                                               tmpf, MROWS, D_, D_);
    final_kernel<<<dim3(MROWS), blk, 0, stream>>>(tmpf, alpha, beta, alpha_s, beta_s,
                                                  (float*)d_out);
}